// Round 1
// baseline (1112.719 us; speedup 1.0000x reference)
//
#include <hip/hip_runtime.h>
#include <stdint.h>

// ---------------------------------------------------------------------------
// TransformerDecoderLayer on gfx950: bf16 MFMA GEMMs + flash attention.
// B=2, T=S=2048, C=1024, H=16, D=64, FF=4096. 4096 token rows.
// ---------------------------------------------------------------------------

typedef __bf16 bf16x8 __attribute__((ext_vector_type(8)));
typedef float  f32x4  __attribute__((ext_vector_type(4)));

#define T_SEQ 2048
#define NROWS 4096   // B*T

__device__ __forceinline__ unsigned short f2bf(float f) {
  union { float f; unsigned int u; } v; v.f = f;
  unsigned int u = v.u;
  return (unsigned short)((u + 0x7FFFu + ((u >> 16) & 1u)) >> 16);  // RNE
}
__device__ __forceinline__ float bf2f(unsigned short h) {
  union { unsigned int u; float f; } v; v.u = ((unsigned int)h) << 16;
  return v.f;
}

// ---------------------------------------------------------------------------
// dtype probe: decide whether d_in tensors are bf16 (flag=1) or fp32 (flag=0).
// If fp32, half of the ushorts are float-mantissa halves with random exponent
// fields -> ~42% "insane" bf16 exponents. If bf16 N(0,1), ~0%.
// ---------------------------------------------------------------------------
__global__ void probe_dtype_kernel(const unsigned short* __restrict__ p,
                                   int* __restrict__ flag) {
  __shared__ int cnt;
  if (threadIdx.x == 0) cnt = 0;
  __syncthreads();
  int bad = 0;
  for (int i = threadIdx.x; i < 4096; i += 256) {
    unsigned short u = p[i];
    int e = (u >> 7) & 0xFF;
    if (u != 0 && (e < 100 || e > 140)) bad++;
  }
  atomicAdd(&cnt, bad);
  __syncthreads();
  if (threadIdx.x == 0) *flag = (cnt < 512) ? 1 : 0;
}

// W [K,N] (fp32 or bf16 per flag) -> Wt [N,K] bf16
__global__ void wtrans_kernel(const void* __restrict__ W,
                              unsigned short* __restrict__ Wt,
                              int K, int N, const int* __restrict__ flag) {
  __shared__ unsigned short tile[32][33];
  const int n0 = blockIdx.x * 32, k0 = blockIdx.y * 32;
  const int c = threadIdx.x & 31, r0 = threadIdx.x >> 5;
  const bool isbf = (*flag != 0);
  for (int r = r0; r < 32; r += 8) {
    unsigned short v;
    if (isbf) v = ((const unsigned short*)W)[(size_t)(k0 + r) * N + n0 + c];
    else      v = f2bf(((const float*)W)[(size_t)(k0 + r) * N + n0 + c]);
    tile[r][c] = v;
  }
  __syncthreads();
  for (int r = r0; r < 32; r += 8)
    Wt[(size_t)(n0 + r) * K + k0 + c] = tile[c][r];
}

// elementwise -> bf16 (8 elems/thread)
__global__ void cvt_to_bf16_kernel(const void* __restrict__ in,
                                   unsigned short* __restrict__ out,
                                   int n, const int* __restrict__ flag) {
  int i = (blockIdx.x * 256 + threadIdx.x) * 8;
  if (i >= n) return;
  if (*flag) {
    *(int4*)&out[i] = *(const int4*)&((const unsigned short*)in)[i];
  } else {
    const float* f = (const float*)in;
    float4 a = *(const float4*)&f[i];
    float4 c = *(const float4*)&f[i + 4];
    ushort4 o1, o2;
    o1.x = f2bf(a.x); o1.y = f2bf(a.y); o1.z = f2bf(a.z); o1.w = f2bf(a.w);
    o2.x = f2bf(c.x); o2.y = f2bf(c.y); o2.z = f2bf(c.z); o2.w = f2bf(c.w);
    *(ushort4*)&out[i] = o1;
    *(ushort4*)&out[i + 4] = o2;
  }
}

// elementwise -> fp32 (4 elems/thread)
__global__ void cvt_to_f32_kernel(const void* __restrict__ in,
                                  float* __restrict__ out,
                                  int n, const int* __restrict__ flag) {
  int i = (blockIdx.x * 256 + threadIdx.x) * 4;
  if (i >= n) return;
  if (*flag) {
    const unsigned short* u = (const unsigned short*)in;
    ushort4 q = *(const ushort4*)&u[i];
    float4 o;
    o.x = bf2f(q.x); o.y = bf2f(q.y); o.z = bf2f(q.z); o.w = bf2f(q.w);
    *(float4*)&out[i] = o;
  } else {
    *(float4*)&out[i] = *(const float4*)&((const float*)in)[i];
  }
}

// LayerNorm over rows of 1024, fp32 in -> bf16 out
__global__ __launch_bounds__(256) void ln_kernel(
    const float* __restrict__ x, const float* __restrict__ g,
    const float* __restrict__ b, unsigned short* __restrict__ out) {
  const int row = blockIdx.x;
  const int t = threadIdx.x;
  const size_t base = (size_t)row * 1024;
  float4 v = *(const float4*)&x[base + t * 4];
  float s1 = v.x + v.y + v.z + v.w;
  float s2 = v.x * v.x + v.y * v.y + v.z * v.z + v.w * v.w;
#pragma unroll
  for (int d = 1; d < 64; d <<= 1) {
    s1 += __shfl_xor(s1, d, 64);
    s2 += __shfl_xor(s2, d, 64);
  }
  __shared__ float a1[4], a2[4];
  if ((t & 63) == 0) { a1[t >> 6] = s1; a2[t >> 6] = s2; }
  __syncthreads();
  s1 = a1[0] + a1[1] + a1[2] + a1[3];
  s2 = a2[0] + a2[1] + a2[2] + a2[3];
  const float mean = s1 * (1.0f / 1024.0f);
  const float var = s2 * (1.0f / 1024.0f) - mean * mean;
  const float rstd = rsqrtf(fmaxf(var, 0.0f) + 1e-5f);
  float4 gv = *(const float4*)&g[t * 4];
  float4 bv = *(const float4*)&b[t * 4];
  ushort4 o;
  o.x = f2bf((v.x - mean) * rstd * gv.x + bv.x);
  o.y = f2bf((v.y - mean) * rstd * gv.y + bv.y);
  o.z = f2bf((v.z - mean) * rstd * gv.z + bv.z);
  o.w = f2bf((v.w - mean) * rstd * gv.w + bv.w);
  *(ushort4*)&out[base + t * 4] = o;
}

// ---------------------------------------------------------------------------
// GEMM: C[M,N] = A[M,K](bf16) @ Bt[N,K](bf16)^T + bias (+relu) (+fp32 resid)
// m97 structure: 128x128 tile, 4 waves 2x2, 4x4 16x16x32 MFMAs/wave, BK=32,
// global_load_lds width-16 staging, 2-barrier K-loop.
// OUTM: 0=f32 out, 1=bf16 out, 2=runtime flag (bf16 if *flag)
// ---------------------------------------------------------------------------
template <int RELU, int RESID, int OUTM>
__global__ __launch_bounds__(256, 2) void gemm_kernel(
    const unsigned short* __restrict__ A, const unsigned short* __restrict__ Bt,
    const float* __restrict__ bias, const float* __restrict__ resid,
    void* __restrict__ outp, int M, int N, int K,
    const int* __restrict__ flag) {
  __shared__ unsigned short lsA[4096];  // [128][32]
  __shared__ unsigned short lsB[4096];  // [128][32]
  const int t = threadIdx.x;
  const int wave = t >> 6, lane = t & 63;
  const int ml = lane & 15, quad = lane >> 4;
  const int wm = (wave >> 1) * 64, wn = (wave & 1) * 64;
  const size_t m0 = (size_t)blockIdx.y * 128;
  const size_t n0 = (size_t)blockIdx.x * 128;

  f32x4 acc[4][4];
  const f32x4 fz = {0.f, 0.f, 0.f, 0.f};
#pragma unroll
  for (int i = 0; i < 4; i++)
#pragma unroll
    for (int j = 0; j < 4; j++) acc[i][j] = fz;

  const int rowL = t >> 2;         // 0..63
  const int colL = (t & 3) * 8;    // 0,8,16,24
  const unsigned short* gA0 = A + (m0 + rowL) * (size_t)K + colL;
  const unsigned short* gA1 = gA0 + (size_t)64 * K;
  const unsigned short* gB0 = Bt + (n0 + rowL) * (size_t)K + colL;
  const unsigned short* gB1 = gB0 + (size_t)64 * K;
  unsigned short* dA0 = &lsA[wave * 512];
  unsigned short* dA1 = &lsA[2048 + wave * 512];
  unsigned short* dB0 = &lsB[wave * 512];
  unsigned short* dB1 = &lsB[2048 + wave * 512];

  for (int k0 = 0; k0 < K; k0 += 32) {
    __syncthreads();
    __builtin_amdgcn_global_load_lds(
        (const __attribute__((address_space(1))) void*)(gA0 + k0),
        (__attribute__((address_space(3))) void*)dA0, 16, 0, 0);
    __builtin_amdgcn_global_load_lds(
        (const __attribute__((address_space(1))) void*)(gA1 + k0),
        (__attribute__((address_space(3))) void*)dA1, 16, 0, 0);
    __builtin_amdgcn_global_load_lds(
        (const __attribute__((address_space(1))) void*)(gB0 + k0),
        (__attribute__((address_space(3))) void*)dB0, 16, 0, 0);
    __builtin_amdgcn_global_load_lds(
        (const __attribute__((address_space(1))) void*)(gB1 + k0),
        (__attribute__((address_space(3))) void*)dB1, 16, 0, 0);
    __syncthreads();
    bf16x8 af[4], bfv[4];
#pragma unroll
    for (int i = 0; i < 4; i++)
      af[i] = *(const bf16x8*)&lsA[(wm + i * 16 + ml) * 32 + quad * 8];
#pragma unroll
    for (int j = 0; j < 4; j++)
      bfv[j] = *(const bf16x8*)&lsB[(wn + j * 16 + ml) * 32 + quad * 8];
#pragma unroll
    for (int i = 0; i < 4; i++)
#pragma unroll
      for (int j = 0; j < 4; j++)
        acc[i][j] = __builtin_amdgcn_mfma_f32_16x16x32_bf16(af[i], bfv[j],
                                                            acc[i][j], 0, 0, 0);
  }

  const bool obf = (OUTM == 1) || (OUTM == 2 && *flag != 0);
#pragma unroll
  for (int j = 0; j < 4; j++) {
    const size_t cg = n0 + wn + j * 16 + ml;
    const float bval = bias[cg];
#pragma unroll
    for (int i = 0; i < 4; i++) {
#pragma unroll
      for (int r = 0; r < 4; r++) {
        const size_t rg = m0 + wm + i * 16 + quad * 4 + r;
        float v = acc[i][j][r] + bval;
        if (RELU) v = fmaxf(v, 0.0f);
        if (RESID) v += resid[rg * N + cg];
        if (obf) ((unsigned short*)outp)[rg * N + cg] = f2bf(v);
        else     ((float*)outp)[rg * N + cg] = v;
      }
    }
  }
}

// ---------------------------------------------------------------------------
// Flash attention: one block = (b, h, 64 q-rows); 4 waves x 16 rows each.
// K-blocks of 32. S=QK^T via 16x16x32 MFMA, online softmax (quad shuffles),
// P round-trips through LDS (C-layout -> A-layout), PV with V transposed.
// ---------------------------------------------------------------------------
template <int CAUSAL>
__global__ __launch_bounds__(256, 2) void attn_kernel(
    const unsigned short* __restrict__ Q, const unsigned short* __restrict__ K,
    const unsigned short* __restrict__ V, unsigned short* __restrict__ O) {
  __shared__ unsigned short Qs[64 * 64];   // [qrow][d]
  __shared__ unsigned short Ks[32 * 64];   // [key][d]
  __shared__ unsigned short Vt[64 * 32];   // [d][key]
  __shared__ unsigned short Ps[4][16 * 32];// per-wave [qrow][key]
  const int t = threadIdx.x;
  const int wave = t >> 6, lane = t & 63;
  const int ml = lane & 15, quad = lane >> 4;
  const int bh = blockIdx.y;
  const int b = bh >> 4, h = bh & 15;
  const int q0 = blockIdx.x * 64;
  const size_t base = ((size_t)b * T_SEQ) * 1024 + (size_t)h * 64;

#pragma unroll
  for (int ch = t; ch < 512; ch += 256) {
    int r = ch >> 3, c = (ch & 7) * 8;
    *(int4*)&Qs[r * 64 + c] = *(const int4*)&Q[base + (size_t)(q0 + r) * 1024 + c];
  }

  f32x4 acc_o[4];
  const f32x4 fz = {0.f, 0.f, 0.f, 0.f};
#pragma unroll
  for (int n = 0; n < 4; n++) acc_o[n] = fz;
  float m_i[4], l_i[4];
#pragma unroll
  for (int r = 0; r < 4; r++) { m_i[r] = -3.0e38f; l_i[r] = 0.0f; }

  const int nkb = CAUSAL ? ((q0 + 64) >> 5) : (T_SEQ >> 5);
  for (int kb = 0; kb < nkb; kb++) {
    __syncthreads();
    {
      int r = t >> 3, c = (t & 7) * 8;
      size_t g = base + (size_t)(kb * 32 + r) * 1024 + c;
      *(int4*)&Ks[r * 64 + c] = *(const int4*)&K[g];
      int4 vv = *(const int4*)&V[g];
      const unsigned short* vs = (const unsigned short*)&vv;
#pragma unroll
      for (int i = 0; i < 8; i++) Vt[(c + i) * 32 + r] = vs[i];
    }
    __syncthreads();

    bf16x8 a0 = *(const bf16x8*)&Qs[(wave * 16 + ml) * 64 + quad * 8];
    bf16x8 a1 = *(const bf16x8*)&Qs[(wave * 16 + ml) * 64 + 32 + quad * 8];
    f32x4 s[2];
#pragma unroll
    for (int nt = 0; nt < 2; nt++) {
      bf16x8 b0 = *(const bf16x8*)&Ks[(nt * 16 + ml) * 64 + quad * 8];
      bf16x8 b1 = *(const bf16x8*)&Ks[(nt * 16 + ml) * 64 + 32 + quad * 8];
      f32x4 acc = fz;
      acc = __builtin_amdgcn_mfma_f32_16x16x32_bf16(a0, b0, acc, 0, 0, 0);
      acc = __builtin_amdgcn_mfma_f32_16x16x32_bf16(a1, b1, acc, 0, 0, 0);
      s[nt] = acc;
    }
#pragma unroll
    for (int nt = 0; nt < 2; nt++)
#pragma unroll
      for (int r = 0; r < 4; r++) {
        float sv = s[nt][r] * 0.125f;
        if (CAUSAL) {
          int kg = kb * 32 + nt * 16 + ml;
          int qg = q0 + wave * 16 + quad * 4 + r;
          if (kg > qg) sv = -3.0e38f;
        }
        s[nt][r] = sv;
      }
    float alpha[4];
#pragma unroll
    for (int r = 0; r < 4; r++) {
      float v = fmaxf(s[0][r], s[1][r]);
#pragma unroll
      for (int d = 1; d < 16; d <<= 1) v = fmaxf(v, __shfl_xor(v, d, 64));
      float mn = fmaxf(m_i[r], v);
      float a = __expf(m_i[r] - mn);
      float p0 = __expf(s[0][r] - mn);
      float p1 = __expf(s[1][r] - mn);
      float rs = p0 + p1;
#pragma unroll
      for (int d = 1; d < 16; d <<= 1) rs += __shfl_xor(rs, d, 64);
      m_i[r] = mn;
      l_i[r] = l_i[r] * a + rs;
      alpha[r] = a;
      s[0][r] = p0;
      s[1][r] = p1;
    }
#pragma unroll
    for (int nt = 0; nt < 2; nt++)
#pragma unroll
      for (int r = 0; r < 4; r++)
        Ps[wave][(quad * 4 + r) * 32 + nt * 16 + ml] = f2bf(s[nt][r]);
#pragma unroll
    for (int n = 0; n < 4; n++)
#pragma unroll
      for (int r = 0; r < 4; r++) acc_o[n][r] *= alpha[r];
    __syncthreads();
    bf16x8 ap = *(const bf16x8*)&Ps[wave][ml * 32 + quad * 8];
#pragma unroll
    for (int n = 0; n < 4; n++) {
      bf16x8 bv = *(const bf16x8*)&Vt[(n * 16 + ml) * 32 + quad * 8];
      acc_o[n] = __builtin_amdgcn_mfma_f32_16x16x32_bf16(ap, bv, acc_o[n], 0, 0, 0);
    }
  }

#pragma unroll
  for (int n = 0; n < 4; n++)
#pragma unroll
    for (int r = 0; r < 4; r++) {
      int qg = q0 + wave * 16 + quad * 4 + r;
      float val = acc_o[n][r] / l_i[r];
      O[base + (size_t)qg * 1024 + n * 16 + ml] = f2bf(val);
    }
}

// ---------------------------------------------------------------------------
extern "C" void kernel_launch(void* const* d_in, const int* in_sizes, int n_in,
                              void* d_out, int out_size, void* d_ws,
                              size_t ws_size, hipStream_t stream) {
  (void)in_sizes; (void)n_in; (void)out_size; (void)ws_size;
  const int M = NROWS;
  const size_t MBy = 1024 * 1024;
  unsigned short* ws16 = (unsigned short*)d_ws;
  char* wsb = (char*)d_ws;

  // ws layout (ushort elems): 10 transposed weights (16M), h, Q, K, V, attn,
  // ffh overlaps QKV+attn, encB; then fp32 xf32, xbuf, params, flag.
  unsigned short* wt[10];
  for (int i = 0; i < 8; i++) wt[i] = ws16 + (size_t)i * 1048576;
  wt[8] = ws16 + 8ull * 1048576;    // ff_w1t [4096,1024]
  wt[9] = ws16 + 12ull * 1048576;   // ff_w2t [1024,4096]
  unsigned short* hbuf  = ws16 + 16ull * 1048576;
  unsigned short* Qb    = ws16 + 20ull * 1048576;
  unsigned short* Kb    = ws16 + 24ull * 1048576;
  unsigned short* Vb    = ws16 + 28ull * 1048576;
  unsigned short* attnb = ws16 + 32ull * 1048576;
  unsigned short* ffh   = ws16 + 20ull * 1048576;  // reuses QKV+attn region
  unsigned short* encB  = ws16 + 36ull * 1048576;
  float* xf32 = (float*)(wsb + 80ull * MBy);
  float* xbuf = (float*)(wsb + 96ull * MBy);
  float* pbuf = (float*)(wsb + 112ull * MBy);
  int* flag   = (int*)(wsb + 113ull * MBy);

  // 1. dtype probe on x
  probe_dtype_kernel<<<1, 256, 0, stream>>>((const unsigned short*)d_in[0], flag);

  // 2. transpose+cast weights to [N,K] bf16
  const int widx[10] = {3, 5, 7, 9, 11, 13, 15, 17, 19, 21};
  const int wK[10] = {1024, 1024, 1024, 1024, 1024, 1024, 1024, 1024, 1024, 4096};
  const int wN[10] = {1024, 1024, 1024, 1024, 1024, 1024, 1024, 1024, 4096, 1024};
  for (int i = 0; i < 10; i++) {
    dim3 g(wN[i] / 32, wK[i] / 32);
    wtrans_kernel<<<g, 256, 0, stream>>>(d_in[widx[i]], wt[i], wK[i], wN[i], flag);
  }

  // 3. stage x (fp32) and encoder outputs (bf16)
  cvt_to_f32_kernel<<<4096, 256, 0, stream>>>(d_in[0], xf32, 4194304, flag);
  cvt_to_bf16_kernel<<<2048, 256, 0, stream>>>(d_in[1], encB, 4194304, flag);

  // 4. stage biases / LN params as fp32
  const int pidx[16] = {4, 6, 8, 10, 12, 14, 16, 18, 20, 22, 23, 24, 25, 26, 27, 28};
  const int pn[16] = {1024, 1024, 1024, 1024, 1024, 1024, 1024, 1024,
                      4096, 1024, 1024, 1024, 1024, 1024, 1024, 1024};
  float* pptr[16];
  {
    size_t po = 0;
    for (int i = 0; i < 16; i++) { pptr[i] = pbuf + po; po += pn[i]; }
  }
  for (int i = 0; i < 16; i++)
    cvt_to_f32_kernel<<<pn[i] / 1024, 256, 0, stream>>>(d_in[pidx[i]], pptr[i],
                                                        pn[i], flag);
  float* sa_b[4] = {pptr[0], pptr[1], pptr[2], pptr[3]};
  float* ca_b[4] = {pptr[4], pptr[5], pptr[6], pptr[7]};
  float* ff_b1 = pptr[8];
  float* ff_b2 = pptr[9];
  float* ln1g = pptr[10]; float* ln1b = pptr[11];
  float* ln2g = pptr[12]; float* ln2b = pptr[13];
  float* ln3g = pptr[14]; float* ln3b = pptr[15];

  dim3 gN8(8, 32);    // N=1024 GEMMs
  dim3 gN32(32, 32);  // N=4096 GEMM
  dim3 gAttn(32, 32); // (T/64, B*H)

  // ---- self attention ----
  ln_kernel<<<4096, 256, 0, stream>>>(xf32, ln1g, ln1b, hbuf);
  gemm_kernel<0, 0, 1><<<gN8, 256, 0, stream>>>(hbuf, wt[0], sa_b[0], nullptr, Qb, M, 1024, 1024, nullptr);
  gemm_kernel<0, 0, 1><<<gN8, 256, 0, stream>>>(hbuf, wt[1], sa_b[1], nullptr, Kb, M, 1024, 1024, nullptr);
  gemm_kernel<0, 0, 1><<<gN8, 256, 0, stream>>>(hbuf, wt[2], sa_b[2], nullptr, Vb, M, 1024, 1024, nullptr);
  attn_kernel<1><<<gAttn, 256, 0, stream>>>(Qb, Kb, Vb, attnb);
  gemm_kernel<0, 1, 0><<<gN8, 256, 0, stream>>>(attnb, wt[3], sa_b[3], xf32, xbuf, M, 1024, 1024, nullptr);

  // ---- cross attention ----
  ln_kernel<<<4096, 256, 0, stream>>>(xbuf, ln2g, ln2b, hbuf);
  gemm_kernel<0, 0, 1><<<gN8, 256, 0, stream>>>(hbuf, wt[4], ca_b[0], nullptr, Qb, M, 1024, 1024, nullptr);
  gemm_kernel<0, 0, 1><<<gN8, 256, 0, stream>>>(encB, wt[5], ca_b[1], nullptr, Kb, M, 1024, 1024, nullptr);
  gemm_kernel<0, 0, 1><<<gN8, 256, 0, stream>>>(encB, wt[6], ca_b[2], nullptr, Vb, M, 1024, 1024, nullptr);
  attn_kernel<0><<<gAttn, 256, 0, stream>>>(Qb, Kb, Vb, attnb);
  gemm_kernel<0, 1, 0><<<gN8, 256, 0, stream>>>(attnb, wt[7], ca_b[3], xbuf, xbuf, M, 1024, 1024, nullptr);

  // ---- feed forward ----
  ln_kernel<<<4096, 256, 0, stream>>>(xbuf, ln3g, ln3b, hbuf);
  gemm_kernel<1, 0, 1><<<gN32, 256, 0, stream>>>(hbuf, wt[8], ff_b1, nullptr, ffh, M, 4096, 1024, nullptr);
  gemm_kernel<0, 1, 2><<<gN8, 256, 0, stream>>>(ffh, wt[9], ff_b2, xbuf, d_out, M, 1024, 4096, flag);
}

// Round 2
// 788.931 us; speedup vs baseline: 1.4104x; 1.4104x over previous
//
#include <hip/hip_runtime.h>
#include <stdint.h>

// ---------------------------------------------------------------------------
// TransformerDecoderLayer on gfx950: bf16 MFMA GEMMs + flash attention.
// B=2, T=S=2048, C=1024, H=16, D=64, FF=4096. 4096 token rows.
// R2: attention rewritten — S^T form (per-lane softmax state), key-permuted
// K staging so the P fragment is built in-lane (no LDS round trip, no
// shuffles), V^T produced directly by the V-projection GEMM (operand swap),
// ktile=64, Q frags cached in registers. Eliminates all scalar LDS writes.
// ---------------------------------------------------------------------------

typedef __bf16 bf16x8 __attribute__((ext_vector_type(8)));
typedef float  f32x4  __attribute__((ext_vector_type(4)));

#define T_SEQ 2048
#define NROWS 4096   // B*T

__device__ __forceinline__ unsigned short f2bf(float f) {
  union { float f; unsigned int u; } v; v.f = f;
  unsigned int u = v.u;
  return (unsigned short)((u + 0x7FFFu + ((u >> 16) & 1u)) >> 16);  // RNE
}
__device__ __forceinline__ float bf2f(unsigned short h) {
  union { unsigned int u; float f; } v; v.u = ((unsigned int)h) << 16;
  return v.f;
}
__device__ __forceinline__ unsigned int pk2(float a, float b) {
  return (unsigned int)f2bf(a) | ((unsigned int)f2bf(b) << 16);
}
union U4 { unsigned int u[4]; bf16x8 v; };

// ---------------------------------------------------------------------------
// dtype probe: bf16 (flag=1) vs fp32 (flag=0) input tensors.
// ---------------------------------------------------------------------------
__global__ void probe_dtype_kernel(const unsigned short* __restrict__ p,
                                   int* __restrict__ flag) {
  __shared__ int cnt;
  if (threadIdx.x == 0) cnt = 0;
  __syncthreads();
  int bad = 0;
  for (int i = threadIdx.x; i < 4096; i += 256) {
    unsigned short u = p[i];
    int e = (u >> 7) & 0xFF;
    if (u != 0 && (e < 100 || e > 140)) bad++;
  }
  atomicAdd(&cnt, bad);
  __syncthreads();
  if (threadIdx.x == 0) *flag = (cnt < 512) ? 1 : 0;
}

// W [K,N] (fp32 or bf16 per flag) -> Wt [N,K] bf16
__global__ void wtrans_kernel(const void* __restrict__ W,
                              unsigned short* __restrict__ Wt,
                              int K, int N, const int* __restrict__ flag) {
  __shared__ unsigned short tile[32][33];
  const int n0 = blockIdx.x * 32, k0 = blockIdx.y * 32;
  const int c = threadIdx.x & 31, r0 = threadIdx.x >> 5;
  const bool isbf = (*flag != 0);
  for (int r = r0; r < 32; r += 8) {
    unsigned short v;
    if (isbf) v = ((const unsigned short*)W)[(size_t)(k0 + r) * N + n0 + c];
    else      v = f2bf(((const float*)W)[(size_t)(k0 + r) * N + n0 + c]);
    tile[r][c] = v;
  }
  __syncthreads();
  for (int r = r0; r < 32; r += 8)
    Wt[(size_t)(n0 + r) * K + k0 + c] = tile[c][r];
}

__global__ void cvt_to_bf16_kernel(const void* __restrict__ in,
                                   unsigned short* __restrict__ out,
                                   int n, const int* __restrict__ flag) {
  int i = (blockIdx.x * 256 + threadIdx.x) * 8;
  if (i >= n) return;
  if (*flag) {
    *(int4*)&out[i] = *(const int4*)&((const unsigned short*)in)[i];
  } else {
    const float* f = (const float*)in;
    float4 a = *(const float4*)&f[i];
    float4 c = *(const float4*)&f[i + 4];
    ushort4 o1, o2;
    o1.x = f2bf(a.x); o1.y = f2bf(a.y); o1.z = f2bf(a.z); o1.w = f2bf(a.w);
    o2.x = f2bf(c.x); o2.y = f2bf(c.y); o2.z = f2bf(c.z); o2.w = f2bf(c.w);
    *(ushort4*)&out[i] = o1;
    *(ushort4*)&out[i + 4] = o2;
  }
}

__global__ void cvt_to_f32_kernel(const void* __restrict__ in,
                                  float* __restrict__ out,
                                  int n, const int* __restrict__ flag) {
  int i = (blockIdx.x * 256 + threadIdx.x) * 4;
  if (i >= n) return;
  if (*flag) {
    const unsigned short* u = (const unsigned short*)in;
    ushort4 q = *(const ushort4*)&u[i];
    float4 o;
    o.x = bf2f(q.x); o.y = bf2f(q.y); o.z = bf2f(q.z); o.w = bf2f(q.w);
    *(float4*)&out[i] = o;
  } else {
    *(float4*)&out[i] = *(const float4*)&((const float*)in)[i];
  }
}

// LayerNorm over rows of 1024, fp32 in -> bf16 out
__global__ __launch_bounds__(256) void ln_kernel(
    const float* __restrict__ x, const float* __restrict__ g,
    const float* __restrict__ b, unsigned short* __restrict__ out) {
  const int row = blockIdx.x;
  const int t = threadIdx.x;
  const size_t base = (size_t)row * 1024;
  float4 v = *(const float4*)&x[base + t * 4];
  float s1 = v.x + v.y + v.z + v.w;
  float s2 = v.x * v.x + v.y * v.y + v.z * v.z + v.w * v.w;
#pragma unroll
  for (int d = 1; d < 64; d <<= 1) {
    s1 += __shfl_xor(s1, d, 64);
    s2 += __shfl_xor(s2, d, 64);
  }
  __shared__ float a1[4], a2[4];
  if ((t & 63) == 0) { a1[t >> 6] = s1; a2[t >> 6] = s2; }
  __syncthreads();
  s1 = a1[0] + a1[1] + a1[2] + a1[3];
  s2 = a2[0] + a2[1] + a2[2] + a2[3];
  const float mean = s1 * (1.0f / 1024.0f);
  const float var = s2 * (1.0f / 1024.0f) - mean * mean;
  const float rstd = rsqrtf(fmaxf(var, 0.0f) + 1e-5f);
  float4 gv = *(const float4*)&g[t * 4];
  float4 bv = *(const float4*)&b[t * 4];
  ushort4 o;
  o.x = f2bf((v.x - mean) * rstd * gv.x + bv.x);
  o.y = f2bf((v.y - mean) * rstd * gv.y + bv.y);
  o.z = f2bf((v.z - mean) * rstd * gv.z + bv.z);
  o.w = f2bf((v.w - mean) * rstd * gv.w + bv.w);
  *(ushort4*)&out[base + t * 4] = o;
}

// ---------------------------------------------------------------------------
// GEMM: C[M,N] = A[M,K](bf16) @ Bt[N,K](bf16)^T + bias (+relu) (+fp32 resid)
// OUTM: 0=f32 out, 1=bf16 out, 2=runtime flag (bf16 if *flag)
// BIASROW: bias indexed by row (for the V^T-producing operand-swapped call)
// SCALE: multiply output by 0.125 (folds 1/sqrt(d) into Q projection; exact)
// ---------------------------------------------------------------------------
template <int RELU, int RESID, int OUTM, int BIASROW, int SCALE>
__global__ __launch_bounds__(256, 2) void gemm_kernel(
    const unsigned short* __restrict__ A, const unsigned short* __restrict__ Bt,
    const float* __restrict__ bias, const float* __restrict__ resid,
    void* __restrict__ outp, int M, int N, int K,
    const int* __restrict__ flag) {
  __shared__ unsigned short lsA[4096];  // [128][32]
  __shared__ unsigned short lsB[4096];  // [128][32]
  const int t = threadIdx.x;
  const int wave = t >> 6, lane = t & 63;
  const int ml = lane & 15, quad = lane >> 4;
  const int wm = (wave >> 1) * 64, wn = (wave & 1) * 64;
  const size_t m0 = (size_t)blockIdx.y * 128;
  const size_t n0 = (size_t)blockIdx.x * 128;

  f32x4 acc[4][4];
  const f32x4 fz = {0.f, 0.f, 0.f, 0.f};
#pragma unroll
  for (int i = 0; i < 4; i++)
#pragma unroll
    for (int j = 0; j < 4; j++) acc[i][j] = fz;

  const int rowL = t >> 2;         // 0..63
  const int colL = (t & 3) * 8;    // 0,8,16,24
  const unsigned short* gA0 = A + (m0 + rowL) * (size_t)K + colL;
  const unsigned short* gA1 = gA0 + (size_t)64 * K;
  const unsigned short* gB0 = Bt + (n0 + rowL) * (size_t)K + colL;
  const unsigned short* gB1 = gB0 + (size_t)64 * K;
  unsigned short* dA0 = &lsA[wave * 512];
  unsigned short* dA1 = &lsA[2048 + wave * 512];
  unsigned short* dB0 = &lsB[wave * 512];
  unsigned short* dB1 = &lsB[2048 + wave * 512];

  for (int k0 = 0; k0 < K; k0 += 32) {
    __syncthreads();
    __builtin_amdgcn_global_load_lds(
        (const __attribute__((address_space(1))) void*)(gA0 + k0),
        (__attribute__((address_space(3))) void*)dA0, 16, 0, 0);
    __builtin_amdgcn_global_load_lds(
        (const __attribute__((address_space(1))) void*)(gA1 + k0),
        (__attribute__((address_space(3))) void*)dA1, 16, 0, 0);
    __builtin_amdgcn_global_load_lds(
        (const __attribute__((address_space(1))) void*)(gB0 + k0),
        (__attribute__((address_space(3))) void*)dB0, 16, 0, 0);
    __builtin_amdgcn_global_load_lds(
        (const __attribute__((address_space(1))) void*)(gB1 + k0),
        (__attribute__((address_space(3))) void*)dB1, 16, 0, 0);
    __syncthreads();
    bf16x8 af[4], bfv[4];
#pragma unroll
    for (int i = 0; i < 4; i++)
      af[i] = *(const bf16x8*)&lsA[(wm + i * 16 + ml) * 32 + quad * 8];
#pragma unroll
    for (int j = 0; j < 4; j++)
      bfv[j] = *(const bf16x8*)&lsB[(wn + j * 16 + ml) * 32 + quad * 8];
#pragma unroll
    for (int i = 0; i < 4; i++)
#pragma unroll
      for (int j = 0; j < 4; j++)
        acc[i][j] = __builtin_amdgcn_mfma_f32_16x16x32_bf16(af[i], bfv[j],
                                                            acc[i][j], 0, 0, 0);
  }

  const bool obf = (OUTM == 1) || (OUTM == 2 && *flag != 0);
#pragma unroll
  for (int j = 0; j < 4; j++) {
    const size_t cg = n0 + wn + j * 16 + ml;
    const float bcol = BIASROW ? 0.0f : bias[cg];
#pragma unroll
    for (int i = 0; i < 4; i++) {
#pragma unroll
      for (int r = 0; r < 4; r++) {
        const size_t rg = m0 + wm + i * 16 + quad * 4 + r;
        const float bval = BIASROW ? bias[rg] : bcol;
        float v = acc[i][j][r] + bval;
        if (SCALE) v *= 0.125f;
        if (RELU) v = fmaxf(v, 0.0f);
        if (RESID) v += resid[rg * N + cg];
        if (obf) ((unsigned short*)outp)[rg * N + cg] = f2bf(v);
        else     ((float*)outp)[rg * N + cg] = v;
      }
    }
  }
}

// ---------------------------------------------------------------------------
// Flash attention, S^T form. Block = (b,h,64 q). Wave w owns q rows
// w*16..w*16+15 (q = ml within wave). ktile=64.
//   S^T = mfma(K_frag, Q_frag): lane holds S^T[key_pos=nt*16+quad*4+r][q=ml]
//   K rows staged at permuted positions: LDS row p holds key kb*64+s(p),
//     s(p) = ((p&16)<<1)|((p&12)<<1)|((p&32)>>3)|(p&3)
//   => P fragment for PV (keys 32h+quad*8+j) is built IN-LANE from
//      p[h],p[2+h] (no shuffles, no LDS round trip).
//   O^T = mfma(VT_frag, P_frag): C col=ml=q, so m/l/alpha are per-lane.
//   Epilogue: LDS transpose (stride 72, b32 packed writes) -> coalesced b128.
// ---------------------------------------------------------------------------
template <int CAUSAL>
__global__ __launch_bounds__(256, 4) void attn_kernel(
    const unsigned short* __restrict__ Q, const unsigned short* __restrict__ K,
    const unsigned short* __restrict__ VT, unsigned short* __restrict__ O) {
  __shared__ unsigned short Ks[4096];   // [key_pos 64][d 64], rows permuted
  __shared__ unsigned short Vs[4096];   // [d 64][key 64] natural
  __shared__ unsigned short Qs[4608];   // [q 64][d 64] staging; epilogue [64][72]
  const int t = threadIdx.x;
  const int wave = t >> 6, lane = t & 63;
  const int ml = lane & 15, quad = lane >> 4;
  const int bh = blockIdx.y, b = bh >> 4, h = bh & 15;
  const int qb = CAUSAL ? ((int)gridDim.x - 1 - (int)blockIdx.x) : (int)blockIdx.x;
  const int q0 = qb * 64;
  const int lr = lane >> 3, lc = (lane & 7) * 8;

  // stage Q [64][64] (once)
  {
    const unsigned short* g0 =
        Q + ((size_t)(b * T_SEQ + q0 + wave * 16 + lr)) * 1024 + h * 64 + lc;
    __builtin_amdgcn_global_load_lds(
        (const __attribute__((address_space(1))) void*)g0,
        (__attribute__((address_space(3))) void*)&Qs[wave * 2 * 512], 16, 0, 0);
    const unsigned short* g1 = g0 + (size_t)8 * 1024;
    __builtin_amdgcn_global_load_lds(
        (const __attribute__((address_space(1))) void*)g1,
        (__attribute__((address_space(3))) void*)&Qs[(wave * 2 + 1) * 512], 16, 0, 0);
  }

  // per-lane permuted K source rows for this wave's 2 chunks
  int sp_[2];
#pragma unroll
  for (int i = 0; i < 2; i++) {
    int p = (wave * 2 + i) * 8 + lr;
    sp_[i] = ((p & 16) << 1) | ((p & 12) << 1) | ((p & 32) >> 3) | (p & 3);
  }
  const unsigned short* Kb_ = K + ((size_t)b * T_SEQ) * 1024 + h * 64 + lc;
  const unsigned short* Vb_ = VT + ((size_t)h * 64) * 4096 + (size_t)b * T_SEQ + lc;

  __syncthreads();
  const bf16x8 aq0 = *(const bf16x8*)&Qs[(wave * 16 + ml) * 64 + quad * 8];
  const bf16x8 aq1 = *(const bf16x8*)&Qs[(wave * 16 + ml) * 64 + 32 + quad * 8];

  f32x4 acc[4];
  const f32x4 fz = {0.f, 0.f, 0.f, 0.f};
#pragma unroll
  for (int n = 0; n < 4; n++) acc[n] = fz;
  float m_i = -3.0e38f, l_i = 0.0f;
  const int q_glob = q0 + wave * 16 + ml;
  const int nkb = CAUSAL ? (qb + 1) : (T_SEQ / 64);

  for (int kb = 0; kb < nkb; kb++) {
    __syncthreads();
#pragma unroll
    for (int i = 0; i < 2; i++) {
      const int c = wave * 2 + i;
      const unsigned short* kg = Kb_ + ((size_t)(kb * 64 + sp_[i])) * 1024;
      __builtin_amdgcn_global_load_lds(
          (const __attribute__((address_space(1))) void*)kg,
          (__attribute__((address_space(3))) void*)&Ks[c * 512], 16, 0, 0);
      const unsigned short* vg = Vb_ + (size_t)(c * 8 + lr) * 4096 + kb * 64;
      __builtin_amdgcn_global_load_lds(
          (const __attribute__((address_space(1))) void*)vg,
          (__attribute__((address_space(3))) void*)&Vs[c * 512], 16, 0, 0);
    }
    __syncthreads();

    f32x4 s[4];
#pragma unroll
    for (int nt = 0; nt < 4; nt++) {
      bf16x8 k0 = *(const bf16x8*)&Ks[(nt * 16 + ml) * 64 + quad * 8];
      bf16x8 k1 = *(const bf16x8*)&Ks[(nt * 16 + ml) * 64 + 32 + quad * 8];
      f32x4 a = fz;
      a = __builtin_amdgcn_mfma_f32_16x16x32_bf16(k0, aq0, a, 0, 0, 0);
      a = __builtin_amdgcn_mfma_f32_16x16x32_bf16(k1, aq1, a, 0, 0, 0);
      s[nt] = a;
    }
    if (CAUSAL && kb == nkb - 1) {  // only the diagonal tile needs masking
#pragma unroll
      for (int nt = 0; nt < 4; nt++)
#pragma unroll
        for (int r = 0; r < 4; r++) {
          int key = kb * 64 + ((nt & 1) << 5) + (quad << 3) + ((nt >> 1) << 2) + r;
          if (key > q_glob) s[nt][r] = -3.0e38f;
        }
    }
    float tm = -3.0e38f;
#pragma unroll
    for (int nt = 0; nt < 4; nt++)
#pragma unroll
      for (int r = 0; r < 4; r++) tm = fmaxf(tm, s[nt][r]);
    tm = fmaxf(tm, __shfl_xor(tm, 16));
    tm = fmaxf(tm, __shfl_xor(tm, 32));
    const float m_new = fmaxf(m_i, tm);
    const float alpha = __expf(m_i - m_new);
    float p[4][4];
    float rs = 0.f;
#pragma unroll
    for (int nt = 0; nt < 4; nt++)
#pragma unroll
      for (int r = 0; r < 4; r++) {
        p[nt][r] = __expf(s[nt][r] - m_new);
        rs += p[nt][r];
      }
    rs += __shfl_xor(rs, 16);
    rs += __shfl_xor(rs, 32);
    l_i = l_i * alpha + rs;
    m_i = m_new;
#pragma unroll
    for (int n = 0; n < 4; n++)
#pragma unroll
      for (int r = 0; r < 4; r++) acc[n][r] *= alpha;

    U4 P0, P1;  // in-lane fragment assembly (key permutation makes this legal)
    P0.u[0] = pk2(p[0][0], p[0][1]); P0.u[1] = pk2(p[0][2], p[0][3]);
    P0.u[2] = pk2(p[2][0], p[2][1]); P0.u[3] = pk2(p[2][2], p[2][3]);
    P1.u[0] = pk2(p[1][0], p[1][1]); P1.u[1] = pk2(p[1][2], p[1][3]);
    P1.u[2] = pk2(p[3][0], p[3][1]); P1.u[3] = pk2(p[3][2], p[3][3]);

#pragma unroll
    for (int n = 0; n < 4; n++) {
      bf16x8 v0 = *(const bf16x8*)&Vs[(n * 16 + ml) * 64 + quad * 8];
      bf16x8 v1 = *(const bf16x8*)&Vs[(n * 16 + ml) * 64 + 32 + quad * 8];
      acc[n] = __builtin_amdgcn_mfma_f32_16x16x32_bf16(v0, P0.v, acc[n], 0, 0, 0);
      acc[n] = __builtin_amdgcn_mfma_f32_16x16x32_bf16(v1, P1.v, acc[n], 0, 0, 0);
    }
  }

  // epilogue: O^T (per-lane q=ml) -> LDS [q][d] stride 72 -> coalesced stores
  const float inv = 1.0f / l_i;
#pragma unroll
  for (int n = 0; n < 4; n++)
#pragma unroll
    for (int rp = 0; rp < 2; rp++) {
      unsigned int u = pk2(acc[n][2 * rp] * inv, acc[n][2 * rp + 1] * inv);
      *(unsigned int*)&Qs[(wave * 16 + ml) * 72 + n * 16 + quad * 4 + 2 * rp] = u;
    }
  __syncthreads();
  {
    const int q = t >> 2, d0 = (t & 3) * 16;
    unsigned short* og = O + ((size_t)(b * T_SEQ + q0 + q)) * 1024 + h * 64 + d0;
    *(int4*)og = *(const int4*)&Qs[q * 72 + d0];
    *(int4*)(og + 8) = *(const int4*)&Qs[q * 72 + d0 + 8];
  }
}

// ---------------------------------------------------------------------------
extern "C" void kernel_launch(void* const* d_in, const int* in_sizes, int n_in,
                              void* d_out, int out_size, void* d_ws,
                              size_t ws_size, hipStream_t stream) {
  (void)in_sizes; (void)n_in; (void)out_size; (void)ws_size;
  const int M = NROWS;
  const size_t MBy = 1024 * 1024;
  unsigned short* ws16 = (unsigned short*)d_ws;
  char* wsb = (char*)d_ws;

  unsigned short* wt[10];
  for (int i = 0; i < 8; i++) wt[i] = ws16 + (size_t)i * 1048576;
  wt[8] = ws16 + 8ull * 1048576;    // ff_w1t [4096,1024]
  wt[9] = ws16 + 12ull * 1048576;   // ff_w2t [1024,4096]
  unsigned short* hbuf  = ws16 + 16ull * 1048576;
  unsigned short* Qb    = ws16 + 20ull * 1048576;
  unsigned short* Kb    = ws16 + 24ull * 1048576;
  unsigned short* Vb    = ws16 + 28ull * 1048576;  // holds V^T [1024][4096]
  unsigned short* attnb = ws16 + 32ull * 1048576;
  unsigned short* ffh   = ws16 + 20ull * 1048576;  // reuses QKV+attn region
  unsigned short* encB  = ws16 + 36ull * 1048576;
  float* xf32 = (float*)(wsb + 80ull * MBy);
  float* xbuf = (float*)(wsb + 96ull * MBy);
  float* pbuf = (float*)(wsb + 112ull * MBy);
  int* flag   = (int*)(wsb + 113ull * MBy);

  probe_dtype_kernel<<<1, 256, 0, stream>>>((const unsigned short*)d_in[0], flag);

  const int widx[10] = {3, 5, 7, 9, 11, 13, 15, 17, 19, 21};
  const int wK[10] = {1024, 1024, 1024, 1024, 1024, 1024, 1024, 1024, 1024, 4096};
  const int wN[10] = {1024, 1024, 1024, 1024, 1024, 1024, 1024, 1024, 4096, 1024};
  for (int i = 0; i < 10; i++) {
    dim3 g(wN[i] / 32, wK[i] / 32);
    wtrans_kernel<<<g, 256, 0, stream>>>(d_in[widx[i]], wt[i], wK[i], wN[i], flag);
  }

  cvt_to_f32_kernel<<<4096, 256, 0, stream>>>(d_in[0], xf32, 4194304, flag);
  cvt_to_bf16_kernel<<<2048, 256, 0, stream>>>(d_in[1], encB, 4194304, flag);

  const int pidx[16] = {4, 6, 8, 10, 12, 14, 16, 18, 20, 22, 23, 24, 25, 26, 27, 28};
  const int pn[16] = {1024, 1024, 1024, 1024, 1024, 1024, 1024, 1024,
                      4096, 1024, 1024, 1024, 1024, 1024, 1024, 1024};
  float* pptr[16];
  {
    size_t po = 0;
    for (int i = 0; i < 16; i++) { pptr[i] = pbuf + po; po += pn[i]; }
  }
  for (int i = 0; i < 16; i++)
    cvt_to_f32_kernel<<<pn[i] / 1024, 256, 0, stream>>>(d_in[pidx[i]], pptr[i],
                                                        pn[i], flag);
  float* sa_b[4] = {pptr[0], pptr[1], pptr[2], pptr[3]};
  float* ca_b[4] = {pptr[4], pptr[5], pptr[6], pptr[7]};
  float* ff_b1 = pptr[8];
  float* ff_b2 = pptr[9];
  float* ln1g = pptr[10]; float* ln1b = pptr[11];
  float* ln2g = pptr[12]; float* ln2b = pptr[13];
  float* ln3g = pptr[14]; float* ln3b = pptr[15];

  dim3 gN8(8, 32);    // [4096 x 1024] GEMMs
  dim3 gN32(32, 32);  // [4096 x 4096] GEMM
  dim3 gVT(32, 8);    // [1024 x 4096] V^T GEMMs (operand-swapped)
  dim3 gAttn(32, 32); // (q-blocks, B*H)

  // ---- self attention ----
  ln_kernel<<<4096, 256, 0, stream>>>(xf32, ln1g, ln1b, hbuf);
  gemm_kernel<0, 0, 1, 0, 1><<<gN8, 256, 0, stream>>>(hbuf, wt[0], sa_b[0], nullptr, Qb, M, 1024, 1024, nullptr);
  gemm_kernel<0, 0, 1, 0, 0><<<gN8, 256, 0, stream>>>(hbuf, wt[1], sa_b[1], nullptr, Kb, M, 1024, 1024, nullptr);
  gemm_kernel<0, 0, 1, 1, 0><<<gVT, 256, 0, stream>>>(wt[2], hbuf, sa_b[2], nullptr, Vb, 1024, 4096, 1024, nullptr);
  attn_kernel<1><<<gAttn, 256, 0, stream>>>(Qb, Kb, Vb, attnb);
  gemm_kernel<0, 1, 0, 0, 0><<<gN8, 256, 0, stream>>>(attnb, wt[3], sa_b[3], xf32, xbuf, M, 1024, 1024, nullptr);

  // ---- cross attention ----
  ln_kernel<<<4096, 256, 0, stream>>>(xbuf, ln2g, ln2b, hbuf);
  gemm_kernel<0, 0, 1, 0, 1><<<gN8, 256, 0, stream>>>(hbuf, wt[4], ca_b[0], nullptr, Qb, M, 1024, 1024, nullptr);
  gemm_kernel<0, 0, 1, 0, 0><<<gN8, 256, 0, stream>>>(encB, wt[5], ca_b[1], nullptr, Kb, M, 1024, 1024, nullptr);
  gemm_kernel<0, 0, 1, 1, 0><<<gVT, 256, 0, stream>>>(wt[6], encB, ca_b[2], nullptr, Vb, 1024, 4096, 1024, nullptr);
  attn_kernel<0><<<gAttn, 256, 0, stream>>>(Qb, Kb, Vb, attnb);
  gemm_kernel<0, 1, 0, 0, 0><<<gN8, 256, 0, stream>>>(attnb, wt[7], ca_b[3], xbuf, xbuf, M, 1024, 1024, nullptr);

  // ---- feed forward ----
  ln_kernel<<<4096, 256, 0, stream>>>(xbuf, ln3g, ln3b, hbuf);
  gemm_kernel<1, 0, 1, 0, 0><<<gN32, 256, 0, stream>>>(hbuf, wt[8], ff_b1, nullptr, ffh, M, 4096, 1024, nullptr);
  gemm_kernel<0, 1, 2, 0, 0><<<gN8, 256, 0, stream>>>(ffh, wt[9], ff_b2, xbuf, d_out, M, 1024, 4096, flag);
}

// Round 3
// 673.732 us; speedup vs baseline: 1.6516x; 1.1710x over previous
//
#include <hip/hip_runtime.h>
#include <stdint.h>

// ---------------------------------------------------------------------------
// TransformerDecoderLayer on gfx950: bf16 MFMA GEMMs + flash attention.
// B=2, T=S=2048, C=1024, H=16, D=64, FF=4096. 4096 token rows.
// R3: GEMM occupancy fix (tile shapes -> >=512 blocks everywhere), BK=64
// (half the barrier drains), fused self-QK projection, fused staging
// kernels (45 -> 20 dispatches), in-place residual stream.
// ---------------------------------------------------------------------------

typedef __bf16 bf16x8 __attribute__((ext_vector_type(8)));
typedef float  f32x4  __attribute__((ext_vector_type(4)));

#define T_SEQ 2048
#define NROWS 4096   // B*T

__device__ __forceinline__ unsigned short f2bf(float f) {
  union { float f; unsigned int u; } v; v.f = f;
  unsigned int u = v.u;
  return (unsigned short)((u + 0x7FFFu + ((u >> 16) & 1u)) >> 16);  // RNE
}
__device__ __forceinline__ float bf2f(unsigned short h) {
  union { unsigned int u; float f; } v; v.u = ((unsigned int)h) << 16;
  return v.f;
}
__device__ __forceinline__ unsigned int pk2(float a, float b) {
  return (unsigned int)f2bf(a) | ((unsigned int)f2bf(b) << 16);
}
union U4 { unsigned int u[4]; bf16x8 v; };

// ---------------------------------------------------------------------------
// dtype probe: bf16 (flag=1) vs fp32 (flag=0) input tensors.
// ---------------------------------------------------------------------------
__global__ void probe_dtype_kernel(const unsigned short* __restrict__ p,
                                   int* __restrict__ flag) {
  __shared__ int cnt;
  if (threadIdx.x == 0) cnt = 0;
  __syncthreads();
  int bad = 0;
  for (int i = threadIdx.x; i < 4096; i += 256) {
    unsigned short u = p[i];
    int e = (u >> 7) & 0xFF;
    if (u != 0 && (e < 100 || e > 140)) bad++;
  }
  atomicAdd(&cnt, bad);
  __syncthreads();
  if (threadIdx.x == 0) *flag = (cnt < 512) ? 1 : 0;
}

// ---------------------------------------------------------------------------
// Fused weight transpose+cast: all 10 weights in one dispatch (16384 blocks).
// W [K,N] -> Wt [N,K] bf16 at wsbase + dstoff.
// ---------------------------------------------------------------------------
struct WTbl {
  const void* src[10];
  int K[10], N[10], start[10];
  unsigned int dstoff[10];  // in elements
};
__global__ void wtrans_fused_kernel(WTbl tbl, unsigned short* __restrict__ wsbase,
                                    const int* __restrict__ flag) {
  __shared__ unsigned short tile[32][33];
  const int lb = blockIdx.x;
  int wi = 0;
#pragma unroll
  for (int i = 1; i < 10; i++) wi = (lb >= tbl.start[i]) ? i : wi;
  const int local = lb - tbl.start[wi];
  const int Nw = tbl.N[wi], Kw = tbl.K[wi];
  const int bx = local & ((Nw >> 5) - 1);   // N/32 is a power of two here
  const int by = local / (Nw >> 5);
  const void* W = tbl.src[wi];
  unsigned short* Wt = wsbase + tbl.dstoff[wi];
  const int n0 = bx * 32, k0 = by * 32;
  const int c = threadIdx.x & 31, r0 = threadIdx.x >> 5;
  const bool isbf = (*flag != 0);
  for (int r = r0; r < 32; r += 8) {
    unsigned short v;
    if (isbf) v = ((const unsigned short*)W)[(size_t)(k0 + r) * Nw + n0 + c];
    else      v = f2bf(((const float*)W)[(size_t)(k0 + r) * Nw + n0 + c]);
    tile[r][c] = v;
  }
  __syncthreads();
  for (int r = r0; r < 32; r += 8)
    Wt[(size_t)(n0 + r) * Kw + k0 + c] = tile[c][r];
}

// ---------------------------------------------------------------------------
// Fused param convert: 19 x 1024 fp32 values into packed pbuf (one dispatch).
// blocks 8..11 read ff_b1 + (blk-8)*1024.
// ---------------------------------------------------------------------------
struct PTbl { const void* p[19]; };
__global__ void param_cvt_kernel(PTbl tbl, float* __restrict__ out,
                                 const int* __restrict__ flag) {
  const int blk = blockIdx.x;
  const int off = (blk >= 8 && blk < 12) ? (blk - 8) * 1024 : 0;
  const void* src = tbl.p[blk];
  const int i = threadIdx.x * 4;
  float4 o;
  if (*flag) {
    const unsigned short* u = (const unsigned short*)src + off;
    ushort4 q = *(const ushort4*)&u[i];
    o.x = bf2f(q.x); o.y = bf2f(q.y); o.z = bf2f(q.z); o.w = bf2f(q.w);
  } else {
    o = *(const float4*)&((const float*)src)[off + i];
  }
  *(float4*)&out[blk * 1024 + i] = o;
}

__global__ void cvt_to_bf16_kernel(const void* __restrict__ in,
                                   unsigned short* __restrict__ out,
                                   int n, const int* __restrict__ flag) {
  int i = (blockIdx.x * 256 + threadIdx.x) * 8;
  if (i >= n) return;
  if (*flag) {
    *(int4*)&out[i] = *(const int4*)&((const unsigned short*)in)[i];
  } else {
    const float* f = (const float*)in;
    float4 a = *(const float4*)&f[i];
    float4 c = *(const float4*)&f[i + 4];
    ushort4 o1, o2;
    o1.x = f2bf(a.x); o1.y = f2bf(a.y); o1.z = f2bf(a.z); o1.w = f2bf(a.w);
    o2.x = f2bf(c.x); o2.y = f2bf(c.y); o2.z = f2bf(c.z); o2.w = f2bf(c.w);
    *(ushort4*)&out[i] = o1;
    *(ushort4*)&out[i + 4] = o2;
  }
}

__global__ void cvt_to_f32_kernel(const void* __restrict__ in,
                                  float* __restrict__ out,
                                  int n, const int* __restrict__ flag) {
  int i = (blockIdx.x * 256 + threadIdx.x) * 4;
  if (i >= n) return;
  if (*flag) {
    const unsigned short* u = (const unsigned short*)in;
    ushort4 q = *(const ushort4*)&u[i];
    float4 o;
    o.x = bf2f(q.x); o.y = bf2f(q.y); o.z = bf2f(q.z); o.w = bf2f(q.w);
    *(float4*)&out[i] = o;
  } else {
    *(float4*)&out[i] = *(const float4*)&((const float*)in)[i];
  }
}

// LayerNorm over rows of 1024, fp32 in -> bf16 out
__global__ __launch_bounds__(256) void ln_kernel(
    const float* __restrict__ x, const float* __restrict__ g,
    const float* __restrict__ b, unsigned short* __restrict__ out) {
  const int row = blockIdx.x;
  const int t = threadIdx.x;
  const size_t base = (size_t)row * 1024;
  float4 v = *(const float4*)&x[base + t * 4];
  float s1 = v.x + v.y + v.z + v.w;
  float s2 = v.x * v.x + v.y * v.y + v.z * v.z + v.w * v.w;
#pragma unroll
  for (int d = 1; d < 64; d <<= 1) {
    s1 += __shfl_xor(s1, d, 64);
    s2 += __shfl_xor(s2, d, 64);
  }
  __shared__ float a1[4], a2[4];
  if ((t & 63) == 0) { a1[t >> 6] = s1; a2[t >> 6] = s2; }
  __syncthreads();
  s1 = a1[0] + a1[1] + a1[2] + a1[3];
  s2 = a2[0] + a2[1] + a2[2] + a2[3];
  const float mean = s1 * (1.0f / 1024.0f);
  const float var = s2 * (1.0f / 1024.0f) - mean * mean;
  const float rstd = rsqrtf(fmaxf(var, 0.0f) + 1e-5f);
  float4 gv = *(const float4*)&g[t * 4];
  float4 bv = *(const float4*)&b[t * 4];
  ushort4 o;
  o.x = f2bf((v.x - mean) * rstd * gv.x + bv.x);
  o.y = f2bf((v.y - mean) * rstd * gv.y + bv.y);
  o.z = f2bf((v.z - mean) * rstd * gv.z + bv.z);
  o.w = f2bf((v.w - mean) * rstd * gv.w + bv.w);
  *(ushort4*)&out[base + t * 4] = o;
}

// ---------------------------------------------------------------------------
// GEMM: C[M,N] = A[M,K](bf16) @ Bt[N,K](bf16)^T + bias (+relu) (+fp32 resid)
// Tiles: (BM,BN) in {(128,128),(128,64),(64,128)}, BK=64.
// OUTM: 0=f32 out, 1=bf16 out, 2=runtime flag (bf16 if *flag)
// BIASROW: bias indexed by row (operand-swapped V^T GEMM)
// SCALEMODE: 0 none, 1 all *0.125, 2 cols<1024 *0.125 (merged QK)
// ---------------------------------------------------------------------------
template <int BM, int BN, int BK, int RELU, int RESID, int OUTM, int BIASROW,
          int SCALEMODE>
__global__ __launch_bounds__(256, 2) void gemm_kernel(
    const unsigned short* __restrict__ A, const unsigned short* __restrict__ Bt,
    const float* __restrict__ bias, const float* __restrict__ resid,
    void* __restrict__ outp, int M, int N, int K,
    const int* __restrict__ flag) {
  constexpr int WX = (BN == 64) ? 1 : 2;
  constexpr int WY = 4 / WX;
  constexpr int WM = BM / WY, WN = BN / WX;
  constexpr int MI = WM / 16, NJ = WN / 16;
  constexpr int ACALLS = BM * BK / 2048;
  constexpr int BCALLS = BN * BK / 2048;
  constexpr int RPC = 2048 / BK;  // rows staged per call
  __shared__ unsigned short lsA[BM * BK];
  __shared__ unsigned short lsB[BN * BK];
  const int t = threadIdx.x;
  const int wave = t >> 6, lane = t & 63;
  const int ml = lane & 15, quad = lane >> 4;
  const int wm = (wave / WX) * WM, wn = (wave % WX) * WN;
  const size_t m0 = (size_t)blockIdx.y * BM;
  const size_t n0 = (size_t)blockIdx.x * BN;

  f32x4 acc[MI][NJ];
  const f32x4 fz = {0.f, 0.f, 0.f, 0.f};
#pragma unroll
  for (int i = 0; i < MI; i++)
#pragma unroll
    for (int j = 0; j < NJ; j++) acc[i][j] = fz;

  const int rowL = t / (BK / 8);
  const int colL = (t % (BK / 8)) * 8;
  const unsigned short* gA = A + (m0 + rowL) * (size_t)K + colL;
  const unsigned short* gB = Bt + (n0 + rowL) * (size_t)K + colL;

  for (int k0 = 0; k0 < K; k0 += BK) {
    __syncthreads();
#pragma unroll
    for (int c = 0; c < ACALLS; c++)
      __builtin_amdgcn_global_load_lds(
          (const __attribute__((address_space(1))) void*)(gA + (size_t)(c * RPC) * K + k0),
          (__attribute__((address_space(3))) void*)&lsA[c * 2048 + wave * 512], 16, 0, 0);
#pragma unroll
    for (int c = 0; c < BCALLS; c++)
      __builtin_amdgcn_global_load_lds(
          (const __attribute__((address_space(1))) void*)(gB + (size_t)(c * RPC) * K + k0),
          (__attribute__((address_space(3))) void*)&lsB[c * 2048 + wave * 512], 16, 0, 0);
    __syncthreads();
#pragma unroll
    for (int h = 0; h < BK / 32; h++) {
      bf16x8 af[MI], bfv[NJ];
#pragma unroll
      for (int i = 0; i < MI; i++)
        af[i] = *(const bf16x8*)&lsA[(wm + i * 16 + ml) * BK + h * 32 + quad * 8];
#pragma unroll
      for (int j = 0; j < NJ; j++)
        bfv[j] = *(const bf16x8*)&lsB[(wn + j * 16 + ml) * BK + h * 32 + quad * 8];
#pragma unroll
      for (int i = 0; i < MI; i++)
#pragma unroll
        for (int j = 0; j < NJ; j++)
          acc[i][j] = __builtin_amdgcn_mfma_f32_16x16x32_bf16(af[i], bfv[j],
                                                              acc[i][j], 0, 0, 0);
    }
  }

  const bool obf = (OUTM == 1) || (OUTM == 2 && *flag != 0);
#pragma unroll
  for (int j = 0; j < NJ; j++) {
    const size_t cg = n0 + wn + j * 16 + ml;
    const float bcol = BIASROW ? 0.0f : bias[cg];
    const float sc = (SCALEMODE == 0) ? 1.0f
                   : (SCALEMODE == 1) ? 0.125f
                                      : (cg < 1024 ? 0.125f : 1.0f);
#pragma unroll
    for (int i = 0; i < MI; i++) {
#pragma unroll
      for (int r = 0; r < 4; r++) {
        const size_t rg = m0 + wm + i * 16 + quad * 4 + r;
        const float bval = BIASROW ? bias[rg] : bcol;
        float v = (acc[i][j][r] + bval) * sc;
        if (RELU) v = fmaxf(v, 0.0f);
        if (RESID) v += resid[rg * N + cg];
        if (obf) ((unsigned short*)outp)[rg * N + cg] = f2bf(v);
        else     ((float*)outp)[rg * N + cg] = v;
      }
    }
  }
}

// ---------------------------------------------------------------------------
// Flash attention, S^T form (see R2 notes). Q/K row strides parameterized so
// self-attention reads the merged QK buffer ([4096][2048]) directly.
// ---------------------------------------------------------------------------
template <int CAUSAL>
__global__ __launch_bounds__(256, 4) void attn_kernel(
    const unsigned short* __restrict__ Q, const unsigned short* __restrict__ K,
    const unsigned short* __restrict__ VT, unsigned short* __restrict__ O,
    int qstride, int kstride) {
  __shared__ unsigned short Ks[4096];   // [key_pos 64][d 64], rows permuted
  __shared__ unsigned short Vs[4096];   // [d 64][key 64] natural
  __shared__ unsigned short Qs[4608];   // [q 64][d 64] staging; epilogue [64][72]
  const int t = threadIdx.x;
  const int wave = t >> 6, lane = t & 63;
  const int ml = lane & 15, quad = lane >> 4;
  const int bh = blockIdx.y, b = bh >> 4, h = bh & 15;
  const int qb = CAUSAL ? ((int)gridDim.x - 1 - (int)blockIdx.x) : (int)blockIdx.x;
  const int q0 = qb * 64;
  const int lr = lane >> 3, lc = (lane & 7) * 8;

  // stage Q [64][64] (once)
  {
    const unsigned short* g0 =
        Q + ((size_t)(b * T_SEQ + q0 + wave * 16 + lr)) * qstride + h * 64 + lc;
    __builtin_amdgcn_global_load_lds(
        (const __attribute__((address_space(1))) void*)g0,
        (__attribute__((address_space(3))) void*)&Qs[wave * 2 * 512], 16, 0, 0);
    const unsigned short* g1 = g0 + (size_t)8 * qstride;
    __builtin_amdgcn_global_load_lds(
        (const __attribute__((address_space(1))) void*)g1,
        (__attribute__((address_space(3))) void*)&Qs[(wave * 2 + 1) * 512], 16, 0, 0);
  }

  // per-lane permuted K source rows for this wave's 2 chunks
  int sp_[2];
#pragma unroll
  for (int i = 0; i < 2; i++) {
    int p = (wave * 2 + i) * 8 + lr;
    sp_[i] = ((p & 16) << 1) | ((p & 12) << 1) | ((p & 32) >> 3) | (p & 3);
  }
  const unsigned short* Kb_ = K + ((size_t)b * T_SEQ) * kstride + h * 64 + lc;
  const unsigned short* Vb_ = VT + ((size_t)h * 64) * 4096 + (size_t)b * T_SEQ + lc;

  __syncthreads();
  const bf16x8 aq0 = *(const bf16x8*)&Qs[(wave * 16 + ml) * 64 + quad * 8];
  const bf16x8 aq1 = *(const bf16x8*)&Qs[(wave * 16 + ml) * 64 + 32 + quad * 8];

  f32x4 acc[4];
  const f32x4 fz = {0.f, 0.f, 0.f, 0.f};
#pragma unroll
  for (int n = 0; n < 4; n++) acc[n] = fz;
  float m_i = -3.0e38f, l_i = 0.0f;
  const int q_glob = q0 + wave * 16 + ml;
  const int nkb = CAUSAL ? (qb + 1) : (T_SEQ / 64);

  for (int kb = 0; kb < nkb; kb++) {
    __syncthreads();
#pragma unroll
    for (int i = 0; i < 2; i++) {
      const int c = wave * 2 + i;
      const unsigned short* kg = Kb_ + ((size_t)(kb * 64 + sp_[i])) * kstride;
      __builtin_amdgcn_global_load_lds(
          (const __attribute__((address_space(1))) void*)kg,
          (__attribute__((address_space(3))) void*)&Ks[c * 512], 16, 0, 0);
      const unsigned short* vg = Vb_ + (size_t)(c * 8 + lr) * 4096 + kb * 64;
      __builtin_amdgcn_global_load_lds(
          (const __attribute__((address_space(1))) void*)vg,
          (__attribute__((address_space(3))) void*)&Vs[c * 512], 16, 0, 0);
    }
    __syncthreads();

    f32x4 s[4];
#pragma unroll
    for (int nt = 0; nt < 4; nt++) {
      bf16x8 k0 = *(const bf16x8*)&Ks[(nt * 16 + ml) * 64 + quad * 8];
      bf16x8 k1 = *(const bf16x8*)&Ks[(nt * 16 + ml) * 64 + 32 + quad * 8];
      f32x4 a = fz;
      a = __builtin_amdgcn_mfma_f32_16x16x32_bf16(k0, aq0, a, 0, 0, 0);
      a = __builtin_amdgcn_mfma_f32_16x16x32_bf16(k1, aq1, a, 0, 0, 0);
      s[nt] = a;
    }
    if (CAUSAL && kb == nkb - 1) {  // only the diagonal tile needs masking
#pragma unroll
      for (int nt = 0; nt < 4; nt++)
#pragma unroll
        for (int r = 0; r < 4; r++) {
          int key = kb * 64 + ((nt & 1) << 5) + (quad << 3) + ((nt >> 1) << 2) + r;
          if (key > q_glob) s[nt][r] = -3.0e38f;
        }
    }
    float tm = -3.0e38f;
#pragma unroll
    for (int nt = 0; nt < 4; nt++)
#pragma unroll
      for (int r = 0; r < 4; r++) tm = fmaxf(tm, s[nt][r]);
    tm = fmaxf(tm, __shfl_xor(tm, 16));
    tm = fmaxf(tm, __shfl_xor(tm, 32));
    const float m_new = fmaxf(m_i, tm);
    const float alpha = __expf(m_i - m_new);
    float p[4][4];
    float rs = 0.f;
#pragma unroll
    for (int nt = 0; nt < 4; nt++)
#pragma unroll
      for (int r = 0; r < 4; r++) {
        p[nt][r] = __expf(s[nt][r] - m_new);
        rs += p[nt][r];
      }
    rs += __shfl_xor(rs, 16);
    rs += __shfl_xor(rs, 32);
    l_i = l_i * alpha + rs;
    m_i = m_new;
#pragma unroll
    for (int n = 0; n < 4; n++)
#pragma unroll
      for (int r = 0; r < 4; r++) acc[n][r] *= alpha;

    U4 P0, P1;  // in-lane fragment assembly (key permutation makes this legal)
    P0.u[0] = pk2(p[0][0], p[0][1]); P0.u[1] = pk2(p[0][2], p[0][3]);
    P0.u[2] = pk2(p[2][0], p[2][1]); P0.u[3] = pk2(p[2][2], p[2][3]);
    P1.u[0] = pk2(p[1][0], p[1][1]); P1.u[1] = pk2(p[1][2], p[1][3]);
    P1.u[2] = pk2(p[3][0], p[3][1]); P1.u[3] = pk2(p[3][2], p[3][3]);

#pragma unroll
    for (int n = 0; n < 4; n++) {
      bf16x8 v0 = *(const bf16x8*)&Vs[(n * 16 + ml) * 64 + quad * 8];
      bf16x8 v1 = *(const bf16x8*)&Vs[(n * 16 + ml) * 64 + 32 + quad * 8];
      acc[n] = __builtin_amdgcn_mfma_f32_16x16x32_bf16(v0, P0.v, acc[n], 0, 0, 0);
      acc[n] = __builtin_amdgcn_mfma_f32_16x16x32_bf16(v1, P1.v, acc[n], 0, 0, 0);
    }
  }

  // epilogue: O^T (per-lane q=ml) -> LDS [q][d] stride 72 -> coalesced stores
  const float inv = 1.0f / l_i;
#pragma unroll
  for (int n = 0; n < 4; n++)
#pragma unroll
    for (int rp = 0; rp < 2; rp++) {
      unsigned int u = pk2(acc[n][2 * rp] * inv, acc[n][2 * rp + 1] * inv);
      *(unsigned int*)&Qs[(wave * 16 + ml) * 72 + n * 16 + quad * 4 + 2 * rp] = u;
    }
  __syncthreads();
  {
    const int q = t >> 2, d0 = (t & 3) * 16;
    unsigned short* og = O + ((size_t)(b * T_SEQ + q0 + q)) * 1024 + h * 64 + d0;
    *(int4*)og = *(const int4*)&Qs[q * 72 + d0];
    *(int4*)(og + 8) = *(const int4*)&Qs[q * 72 + d0 + 8];
  }
}

// ---------------------------------------------------------------------------
extern "C" void kernel_launch(void* const* d_in, const int* in_sizes, int n_in,
                              void* d_out, int out_size, void* d_ws,
                              size_t ws_size, hipStream_t stream) {
  (void)in_sizes; (void)n_in; (void)out_size; (void)ws_size;
  const size_t MEG = 1048576;
  unsigned short* ws16 = (unsigned short*)d_ws;
  char* wsb = (char*)d_ws;

  // bf16 region (elements):
  // wt[0..7] @ i*1M; ff_w1t @ 8M (4M); ff_w2t @ 12M (4M)
  unsigned short* wt[10];
  for (int i = 0; i < 8; i++) wt[i] = ws16 + (size_t)i * MEG;
  wt[8] = ws16 + 8 * MEG;
  wt[9] = ws16 + 12 * MEG;
  unsigned short* encB  = ws16 + 16 * MEG;  // 4M
  unsigned short* hbuf  = ws16 + 20 * MEG;  // 4M
  unsigned short* QKb   = ws16 + 24 * MEG;  // 8M  [4096][2048]
  unsigned short* Qb    = ws16 + 32 * MEG;  // 4M
  unsigned short* Kb    = ws16 + 36 * MEG;  // 4M
  unsigned short* Vb    = ws16 + 40 * MEG;  // 4M  V^T [1024][4096]
  unsigned short* attnb = ws16 + 44 * MEG;  // 4M
  unsigned short* ffh   = ws16 + 24 * MEG;  // 16M, reuses QKb/Qb/Kb (dead)
  float* xf32 = (float*)(wsb + 96 * MEG);   // fp32 residual stream, 16 MB
  float* pbuf = (float*)(wsb + 112 * MEG);  // 19456 floats
  int* flag   = (int*)(wsb + 113 * MEG);

  probe_dtype_kernel<<<1, 256, 0, stream>>>((const unsigned short*)d_in[0], flag);

  // fused weight transpose (10 weights, one dispatch)
  {
    WTbl tb;
    const int widx[10] = {3, 5, 7, 9, 11, 13, 15, 17, 19, 21};
    int st = 0;
    for (int i = 0; i < 10; i++) {
      tb.src[i] = d_in[widx[i]];
      tb.K[i] = (i == 9) ? 4096 : 1024;
      tb.N[i] = (i == 8) ? 4096 : 1024;
      tb.start[i] = st;
      st += (tb.K[i] / 32) * (tb.N[i] / 32);
      tb.dstoff[i] = (unsigned int)((i < 8) ? i * MEG : (i == 8 ? 8 * MEG : 12 * MEG));
    }
    wtrans_fused_kernel<<<16384, 256, 0, stream>>>(tb, ws16, flag);
  }

  cvt_to_f32_kernel<<<4096, 256, 0, stream>>>(d_in[0], xf32, 4194304, flag);
  cvt_to_bf16_kernel<<<2048, 256, 0, stream>>>(d_in[1], encB, 4194304, flag);

  // fused param convert (one dispatch): pbuf packed layout
  {
    PTbl pt;
    const int pidx[19] = {4, 6, 8, 10, 12, 14, 16, 18,
                          20, 20, 20, 20, 22, 23, 24, 25, 26, 27, 28};
    for (int i = 0; i < 19; i++) pt.p[i] = d_in[pidx[i]];
    param_cvt_kernel<<<19, 256, 0, stream>>>(pt, pbuf, flag);
  }
  float* bqk_sa = pbuf;            // sa_bq ++ sa_bk (contiguous 2048)
  float* bv_sa  = pbuf + 2048;
  float* bo_sa  = pbuf + 3072;
  float* bq_ca  = pbuf + 4096;
  float* bk_ca  = pbuf + 5120;
  float* bv_ca  = pbuf + 6144;
  float* bo_ca  = pbuf + 7168;
  float* ff_b1p = pbuf + 8192;
  float* ff_b2p = pbuf + 12288;
  float* ln1g = pbuf + 13312; float* ln1b = pbuf + 14336;
  float* ln2g = pbuf + 15360; float* ln2b = pbuf + 16384;
  float* ln3g = pbuf + 17408; float* ln3b = pbuf + 18432;

  dim3 gQK(16, 32);   // N=2048, BM=128/BN=128 -> 512 blocks
  dim3 gP(16, 32);    // N=1024, BM=128/BN=64  -> 512 blocks
  dim3 gVT(64, 8);    // M=1024/N=4096, BM=128/BN=64 -> 512 blocks
  dim3 gFF1(32, 32);  // N=4096, BM=128/BN=128 -> 1024 blocks
  dim3 gFF2(8, 64);   // N=1024, BM=64/BN=128  -> 512 blocks
  dim3 gAttn(32, 32);

  // ---- self attention ----
  ln_kernel<<<4096, 256, 0, stream>>>(xf32, ln1g, ln1b, hbuf);
  gemm_kernel<128, 128, 64, 0, 0, 1, 0, 2><<<gQK, 256, 0, stream>>>(
      hbuf, wt[0], bqk_sa, nullptr, QKb, NROWS, 2048, 1024, nullptr);
  gemm_kernel<128, 64, 64, 0, 0, 1, 1, 0><<<gVT, 256, 0, stream>>>(
      wt[2], hbuf, bv_sa, nullptr, Vb, 1024, 4096, 1024, nullptr);
  attn_kernel<1><<<gAttn, 256, 0, stream>>>(QKb, QKb + 1024, Vb, attnb, 2048, 2048);
  gemm_kernel<128, 64, 64, 0, 1, 0, 0, 0><<<gP, 256, 0, stream>>>(
      attnb, wt[3], bo_sa, xf32, xf32, NROWS, 1024, 1024, nullptr);

  // ---- cross attention ----
  ln_kernel<<<4096, 256, 0, stream>>>(xf32, ln2g, ln2b, hbuf);
  gemm_kernel<128, 64, 64, 0, 0, 1, 0, 1><<<gP, 256, 0, stream>>>(
      hbuf, wt[4], bq_ca, nullptr, Qb, NROWS, 1024, 1024, nullptr);
  gemm_kernel<128, 64, 64, 0, 0, 1, 0, 0><<<gP, 256, 0, stream>>>(
      encB, wt[5], bk_ca, nullptr, Kb, NROWS, 1024, 1024, nullptr);
  gemm_kernel<128, 64, 64, 0, 0, 1, 1, 0><<<gVT, 256, 0, stream>>>(
      wt[6], encB, bv_ca, nullptr, Vb, 1024, 4096, 1024, nullptr);
  attn_kernel<0><<<gAttn, 256, 0, stream>>>(Qb, Kb, Vb, attnb, 1024, 1024);
  gemm_kernel<128, 64, 64, 0, 1, 0, 0, 0><<<gP, 256, 0, stream>>>(
      attnb, wt[7], bo_ca, xf32, xf32, NROWS, 1024, 1024, nullptr);

  // ---- feed forward ----
  ln_kernel<<<4096, 256, 0, stream>>>(xf32, ln3g, ln3b, hbuf);
  gemm_kernel<128, 128, 64, 1, 0, 1, 0, 0><<<gFF1, 256, 0, stream>>>(
      hbuf, wt[8], ff_b1p, nullptr, ffh, NROWS, 4096, 1024, nullptr);
  gemm_kernel<64, 128, 64, 0, 1, 2, 0, 0><<<gFF2, 256, 0, stream>>>(
      ffh, wt[9], ff_b2p, xf32, d_out, NROWS, 1024, 4096, flag);
}

// Round 4
// 633.433 us; speedup vs baseline: 1.7566x; 1.0636x over previous
//
#include <hip/hip_runtime.h>
#include <stdint.h>

// ---------------------------------------------------------------------------
// TransformerDecoderLayer on gfx950: bf16 MFMA GEMMs + flash attention.
// B=2, T=S=2048, C=1024, H=16, D=64, FF=4096. 4096 token rows.
// R4: XOR chunk swizzle on all LDS tiles (128B row stride made every
// ds_read_b128 ~8-way bank-conflicted: 2.5e7 conflict-cycles in attn).
// Stage LDS[r][j] = G[r][j^(r&7)] via swizzled global source column (legal
// under global_load_lds lane-contiguity), read chunk c at c^(r&7).
// Also: exp2f softmax with log2(e) folded into the Q-projection scale.
// ---------------------------------------------------------------------------

typedef __bf16 bf16x8 __attribute__((ext_vector_type(8)));
typedef float  f32x4  __attribute__((ext_vector_type(4)));

#define T_SEQ 2048
#define NROWS 4096   // B*T
#define QSCALE 0.18033688011112042f   // 0.125 * log2(e)

__device__ __forceinline__ unsigned short f2bf(float f) {
  union { float f; unsigned int u; } v; v.f = f;
  unsigned int u = v.u;
  return (unsigned short)((u + 0x7FFFu + ((u >> 16) & 1u)) >> 16);  // RNE
}
__device__ __forceinline__ float bf2f(unsigned short h) {
  union { unsigned int u; float f; } v; v.u = ((unsigned int)h) << 16;
  return v.f;
}
__device__ __forceinline__ unsigned int pk2(float a, float b) {
  return (unsigned int)f2bf(a) | ((unsigned int)f2bf(b) << 16);
}
union U4 { unsigned int u[4]; bf16x8 v; };

// ---------------------------------------------------------------------------
// dtype probe: bf16 (flag=1) vs fp32 (flag=0) input tensors.
// ---------------------------------------------------------------------------
__global__ void probe_dtype_kernel(const unsigned short* __restrict__ p,
                                   int* __restrict__ flag) {
  __shared__ int cnt;
  if (threadIdx.x == 0) cnt = 0;
  __syncthreads();
  int bad = 0;
  for (int i = threadIdx.x; i < 4096; i += 256) {
    unsigned short u = p[i];
    int e = (u >> 7) & 0xFF;
    if (u != 0 && (e < 100 || e > 140)) bad++;
  }
  atomicAdd(&cnt, bad);
  __syncthreads();
  if (threadIdx.x == 0) *flag = (cnt < 512) ? 1 : 0;
}

// ---------------------------------------------------------------------------
// Fused weight transpose+cast: all 10 weights in one dispatch (16384 blocks).
// ---------------------------------------------------------------------------
struct WTbl {
  const void* src[10];
  int K[10], N[10], start[10];
  unsigned int dstoff[10];  // in elements
};
__global__ void wtrans_fused_kernel(WTbl tbl, unsigned short* __restrict__ wsbase,
                                    const int* __restrict__ flag) {
  __shared__ unsigned short tile[32][33];
  const int lb = blockIdx.x;
  int wi = 0;
#pragma unroll
  for (int i = 1; i < 10; i++) wi = (lb >= tbl.start[i]) ? i : wi;
  const int local = lb - tbl.start[wi];
  const int Nw = tbl.N[wi], Kw = tbl.K[wi];
  const int bx = local & ((Nw >> 5) - 1);
  const int by = local / (Nw >> 5);
  const void* W = tbl.src[wi];
  unsigned short* Wt = wsbase + tbl.dstoff[wi];
  const int n0 = bx * 32, k0 = by * 32;
  const int c = threadIdx.x & 31, r0 = threadIdx.x >> 5;
  const bool isbf = (*flag != 0);
  for (int r = r0; r < 32; r += 8) {
    unsigned short v;
    if (isbf) v = ((const unsigned short*)W)[(size_t)(k0 + r) * Nw + n0 + c];
    else      v = f2bf(((const float*)W)[(size_t)(k0 + r) * Nw + n0 + c]);
    tile[r][c] = v;
  }
  __syncthreads();
  for (int r = r0; r < 32; r += 8)
    Wt[(size_t)(n0 + r) * Kw + k0 + c] = tile[c][r];
}

// ---------------------------------------------------------------------------
// Fused param convert: 19 x 1024 fp32 values into packed pbuf (one dispatch).
// ---------------------------------------------------------------------------
struct PTbl { const void* p[19]; };
__global__ void param_cvt_kernel(PTbl tbl, float* __restrict__ out,
                                 const int* __restrict__ flag) {
  const int blk = blockIdx.x;
  const int off = (blk >= 8 && blk < 12) ? (blk - 8) * 1024 : 0;
  const void* src = tbl.p[blk];
  const int i = threadIdx.x * 4;
  float4 o;
  if (*flag) {
    const unsigned short* u = (const unsigned short*)src + off;
    ushort4 q = *(const ushort4*)&u[i];
    o.x = bf2f(q.x); o.y = bf2f(q.y); o.z = bf2f(q.z); o.w = bf2f(q.w);
  } else {
    o = *(const float4*)&((const float*)src)[off + i];
  }
  *(float4*)&out[blk * 1024 + i] = o;
}

__global__ void cvt_to_bf16_kernel(const void* __restrict__ in,
                                   unsigned short* __restrict__ out,
                                   int n, const int* __restrict__ flag) {
  int i = (blockIdx.x * 256 + threadIdx.x) * 8;
  if (i >= n) return;
  if (*flag) {
    *(int4*)&out[i] = *(const int4*)&((const unsigned short*)in)[i];
  } else {
    const float* f = (const float*)in;
    float4 a = *(const float4*)&f[i];
    float4 c = *(const float4*)&f[i + 4];
    ushort4 o1, o2;
    o1.x = f2bf(a.x); o1.y = f2bf(a.y); o1.z = f2bf(a.z); o1.w = f2bf(a.w);
    o2.x = f2bf(c.x); o2.y = f2bf(c.y); o2.z = f2bf(c.z); o2.w = f2bf(c.w);
    *(ushort4*)&out[i] = o1;
    *(ushort4*)&out[i + 4] = o2;
  }
}

__global__ void cvt_to_f32_kernel(const void* __restrict__ in,
                                  float* __restrict__ out,
                                  int n, const int* __restrict__ flag) {
  int i = (blockIdx.x * 256 + threadIdx.x) * 4;
  if (i >= n) return;
  if (*flag) {
    const unsigned short* u = (const unsigned short*)in;
    ushort4 q = *(const ushort4*)&u[i];
    float4 o;
    o.x = bf2f(q.x); o.y = bf2f(q.y); o.z = bf2f(q.z); o.w = bf2f(q.w);
    *(float4*)&out[i] = o;
  } else {
    *(float4*)&out[i] = *(const float4*)&((const float*)in)[i];
  }
}

// LayerNorm over rows of 1024, fp32 in -> bf16 out
__global__ __launch_bounds__(256) void ln_kernel(
    const float* __restrict__ x, const float* __restrict__ g,
    const float* __restrict__ b, unsigned short* __restrict__ out) {
  const int row = blockIdx.x;
  const int t = threadIdx.x;
  const size_t base = (size_t)row * 1024;
  float4 v = *(const float4*)&x[base + t * 4];
  float s1 = v.x + v.y + v.z + v.w;
  float s2 = v.x * v.x + v.y * v.y + v.z * v.z + v.w * v.w;
#pragma unroll
  for (int d = 1; d < 64; d <<= 1) {
    s1 += __shfl_xor(s1, d, 64);
    s2 += __shfl_xor(s2, d, 64);
  }
  __shared__ float a1[4], a2[4];
  if ((t & 63) == 0) { a1[t >> 6] = s1; a2[t >> 6] = s2; }
  __syncthreads();
  s1 = a1[0] + a1[1] + a1[2] + a1[3];
  s2 = a2[0] + a2[1] + a2[2] + a2[3];
  const float mean = s1 * (1.0f / 1024.0f);
  const float var = s2 * (1.0f / 1024.0f) - mean * mean;
  const float rstd = rsqrtf(fmaxf(var, 0.0f) + 1e-5f);
  float4 gv = *(const float4*)&g[t * 4];
  float4 bv = *(const float4*)&b[t * 4];
  ushort4 o;
  o.x = f2bf((v.x - mean) * rstd * gv.x + bv.x);
  o.y = f2bf((v.y - mean) * rstd * gv.y + bv.y);
  o.z = f2bf((v.z - mean) * rstd * gv.z + bv.z);
  o.w = f2bf((v.w - mean) * rstd * gv.w + bv.w);
  *(ushort4*)&out[base + t * 4] = o;
}

// ---------------------------------------------------------------------------
// GEMM: C[M,N] = A[M,K](bf16) @ Bt[N,K](bf16)^T + bias (+relu) (+fp32 resid)
// BK=64 fixed. LDS tiles XOR-chunk-swizzled: LDS[r][j] = G[r][j^(r&7)]
// (16B chunks), staged by swizzling the per-lane global source column.
// OUTM: 0=f32 out, 1=bf16 out, 2=runtime flag (bf16 if *flag)
// BIASROW: bias indexed by row.  SCALEMODE: 0 none, 1 all *QSCALE,
// 2 cols<1024 *QSCALE (merged self-QK projection; K part unscaled).
// ---------------------------------------------------------------------------
template <int BM, int BN, int BK, int RELU, int RESID, int OUTM, int BIASROW,
          int SCALEMODE>
__global__ __launch_bounds__(256, 2) void gemm_kernel(
    const unsigned short* __restrict__ A, const unsigned short* __restrict__ Bt,
    const float* __restrict__ bias, const float* __restrict__ resid,
    void* __restrict__ outp, int M, int N, int K,
    const int* __restrict__ flag) {
  static_assert(BK == 64, "swizzle assumes 8 chunks/row");
  constexpr int WX = (BN == 64) ? 1 : 2;
  constexpr int WY = 4 / WX;
  constexpr int WM = BM / WY, WN = BN / WX;
  constexpr int MI = WM / 16, NJ = WN / 16;
  constexpr int ACALLS = BM * BK / 2048;
  constexpr int BCALLS = BN * BK / 2048;
  constexpr int RPC = 2048 / BK;  // rows staged per call (32)
  __shared__ unsigned short lsA[BM * BK];
  __shared__ unsigned short lsB[BN * BK];
  const int t = threadIdx.x;
  const int wave = t >> 6, lane = t & 63;
  const int ml = lane & 15, quad = lane >> 4;
  const int cx = ml & 7;          // read-side XOR key (row&7 for all rows used)
  const int wm = (wave / WX) * WM, wn = (wave % WX) * WN;
  const size_t m0 = (size_t)blockIdx.y * BM;
  const size_t n0 = (size_t)blockIdx.x * BN;

  f32x4 acc[MI][NJ];
  const f32x4 fz = {0.f, 0.f, 0.f, 0.f};
#pragma unroll
  for (int i = 0; i < MI; i++)
#pragma unroll
    for (int j = 0; j < NJ; j++) acc[i][j] = fz;

  const int rowL = t >> 3;                            // global row within tile
  const int colL = (((t & 7) ^ ((t >> 3) & 7)) * 8);  // swizzled source chunk
  const unsigned short* gA = A + (m0 + rowL) * (size_t)K + colL;
  const unsigned short* gB = Bt + (n0 + rowL) * (size_t)K + colL;

  for (int k0 = 0; k0 < K; k0 += BK) {
    __syncthreads();
#pragma unroll
    for (int c = 0; c < ACALLS; c++)
      __builtin_amdgcn_global_load_lds(
          (const __attribute__((address_space(1))) void*)(gA + (size_t)(c * RPC) * K + k0),
          (__attribute__((address_space(3))) void*)&lsA[c * 2048 + wave * 512], 16, 0, 0);
#pragma unroll
    for (int c = 0; c < BCALLS; c++)
      __builtin_amdgcn_global_load_lds(
          (const __attribute__((address_space(1))) void*)(gB + (size_t)(c * RPC) * K + k0),
          (__attribute__((address_space(3))) void*)&lsB[c * 2048 + wave * 512], 16, 0, 0);
    __syncthreads();
#pragma unroll
    for (int h = 0; h < BK / 32; h++) {
      bf16x8 af[MI], bfv[NJ];
#pragma unroll
      for (int i = 0; i < MI; i++)
        af[i] = *(const bf16x8*)
            &lsA[(wm + i * 16 + ml) * BK + (((h * 4 + quad) ^ cx) * 8)];
#pragma unroll
      for (int j = 0; j < NJ; j++)
        bfv[j] = *(const bf16x8*)
            &lsB[(wn + j * 16 + ml) * BK + (((h * 4 + quad) ^ cx) * 8)];
#pragma unroll
      for (int i = 0; i < MI; i++)
#pragma unroll
        for (int j = 0; j < NJ; j++)
          acc[i][j] = __builtin_amdgcn_mfma_f32_16x16x32_bf16(af[i], bfv[j],
                                                              acc[i][j], 0, 0, 0);
    }
  }

  const bool obf = (OUTM == 1) || (OUTM == 2 && *flag != 0);
#pragma unroll
  for (int j = 0; j < NJ; j++) {
    const size_t cg = n0 + wn + j * 16 + ml;
    const float bcol = BIASROW ? 0.0f : bias[cg];
    const float sc = (SCALEMODE == 0) ? 1.0f
                   : (SCALEMODE == 1) ? QSCALE
                                      : (cg < 1024 ? QSCALE : 1.0f);
#pragma unroll
    for (int i = 0; i < MI; i++) {
#pragma unroll
      for (int r = 0; r < 4; r++) {
        const size_t rg = m0 + wm + i * 16 + quad * 4 + r;
        const float bval = BIASROW ? bias[rg] : bcol;
        float v = (acc[i][j][r] + bval) * sc;
        if (RELU) v = fmaxf(v, 0.0f);
        if (RESID) v += resid[rg * N + cg];
        if (obf) ((unsigned short*)outp)[rg * N + cg] = f2bf(v);
        else     ((float*)outp)[rg * N + cg] = v;
      }
    }
  }
}

// ---------------------------------------------------------------------------
// Flash attention, S^T form, XOR-chunk-swizzled LDS (see GEMM note).
// Scores arrive pre-scaled by 0.125*log2(e) -> softmax in base 2 (exp2f).
// ---------------------------------------------------------------------------
template <int CAUSAL>
__global__ __launch_bounds__(256, 4) void attn_kernel(
    const unsigned short* __restrict__ Q, const unsigned short* __restrict__ K,
    const unsigned short* __restrict__ VT, unsigned short* __restrict__ O,
    int qstride, int kstride) {
  __shared__ unsigned short Ks[4096];   // [key_pos 64][d 64], rows permuted
  __shared__ unsigned short Vs[4096];   // [d 64][key 64]
  __shared__ unsigned short Qs[4608];   // [q 64][d 64]; epilogue [64][72]
  const int t = threadIdx.x;
  const int wave = t >> 6, lane = t & 63;
  const int ml = lane & 15, quad = lane >> 4;
  const int cx = ml & 7;  // read-side XOR key
  const int bh = blockIdx.y, b = bh >> 4, h = bh & 15;
  const int qb = CAUSAL ? ((int)gridDim.x - 1 - (int)blockIdx.x) : (int)blockIdx.x;
  const int q0 = qb * 64;
  const int lr = lane >> 3;
  const int scol = (((lane & 7) ^ lr) * 8);  // swizzled source chunk (stage)

  // stage Q [64][64] (once), swizzled
  {
    const unsigned short* g0 =
        Q + ((size_t)(b * T_SEQ + q0 + wave * 16 + lr)) * qstride + h * 64 + scol;
    __builtin_amdgcn_global_load_lds(
        (const __attribute__((address_space(1))) void*)g0,
        (__attribute__((address_space(3))) void*)&Qs[wave * 2 * 512], 16, 0, 0);
    const unsigned short* g1 = g0 + (size_t)8 * qstride;
    __builtin_amdgcn_global_load_lds(
        (const __attribute__((address_space(1))) void*)g1,
        (__attribute__((address_space(3))) void*)&Qs[(wave * 2 + 1) * 512], 16, 0, 0);
  }

  // per-lane permuted K source rows for this wave's 2 chunks
  int sp_[2];
#pragma unroll
  for (int i = 0; i < 2; i++) {
    int p = (wave * 2 + i) * 8 + lr;
    sp_[i] = ((p & 16) << 1) | ((p & 12) << 1) | ((p & 32) >> 3) | (p & 3);
  }
  const unsigned short* Kb_ = K + ((size_t)b * T_SEQ) * kstride + h * 64 + scol;
  const unsigned short* Vb_ = VT + ((size_t)h * 64) * 4096 + (size_t)b * T_SEQ + scol;

  __syncthreads();
  const bf16x8 aq0 = *(const bf16x8*)&Qs[(wave * 16 + ml) * 64 + ((quad ^ cx) * 8)];
  const bf16x8 aq1 = *(const bf16x8*)&Qs[(wave * 16 + ml) * 64 + (((quad + 4) ^ cx) * 8)];

  f32x4 acc[4];
  const f32x4 fz = {0.f, 0.f, 0.f, 0.f};
#pragma unroll
  for (int n = 0; n < 4; n++) acc[n] = fz;
  float m_i = -3.0e38f, l_i = 0.0f;
  const int q_glob = q0 + wave * 16 + ml;
  const int nkb = CAUSAL ? (qb + 1) : (T_SEQ / 64);

  for (int kb = 0; kb < nkb; kb++) {
    __syncthreads();
#pragma unroll
    for (int i = 0; i < 2; i++) {
      const int c = wave * 2 + i;
      const unsigned short* kg = Kb_ + ((size_t)(kb * 64 + sp_[i])) * kstride;
      __builtin_amdgcn_global_load_lds(
          (const __attribute__((address_space(1))) void*)kg,
          (__attribute__((address_space(3))) void*)&Ks[c * 512], 16, 0, 0);
      const unsigned short* vg = Vb_ + (size_t)(c * 8 + lr) * 4096 + kb * 64;
      __builtin_amdgcn_global_load_lds(
          (const __attribute__((address_space(1))) void*)vg,
          (__attribute__((address_space(3))) void*)&Vs[c * 512], 16, 0, 0);
    }
    __syncthreads();

    f32x4 s[4];
#pragma unroll
    for (int nt = 0; nt < 4; nt++) {
      bf16x8 k0 = *(const bf16x8*)&Ks[(nt * 16 + ml) * 64 + ((quad ^ cx) * 8)];
      bf16x8 k1 = *(const bf16x8*)&Ks[(nt * 16 + ml) * 64 + (((quad + 4) ^ cx) * 8)];
      f32x4 a = fz;
      a = __builtin_amdgcn_mfma_f32_16x16x32_bf16(k0, aq0, a, 0, 0, 0);
      a = __builtin_amdgcn_mfma_f32_16x16x32_bf16(k1, aq1, a, 0, 0, 0);
      s[nt] = a;
    }
    if (CAUSAL && kb == nkb - 1) {  // only the diagonal tile needs masking
#pragma unroll
      for (int nt = 0; nt < 4; nt++)
#pragma unroll
        for (int r = 0; r < 4; r++) {
          int key = kb * 64 + ((nt & 1) << 5) + (quad << 3) + ((nt >> 1) << 2) + r;
          if (key > q_glob) s[nt][r] = -3.0e38f;
        }
    }
    float tm = -3.0e38f;
#pragma unroll
    for (int nt = 0; nt < 4; nt++)
#pragma unroll
      for (int r = 0; r < 4; r++) tm = fmaxf(tm, s[nt][r]);
    tm = fmaxf(tm, __shfl_xor(tm, 16));
    tm = fmaxf(tm, __shfl_xor(tm, 32));
    const float m_new = fmaxf(m_i, tm);
    const float alpha = exp2f(m_i - m_new);
    float p[4][4];
    float rs = 0.f;
#pragma unroll
    for (int nt = 0; nt < 4; nt++)
#pragma unroll
      for (int r = 0; r < 4; r++) {
        p[nt][r] = exp2f(s[nt][r] - m_new);
        rs += p[nt][r];
      }
    rs += __shfl_xor(rs, 16);
    rs += __shfl_xor(rs, 32);
    l_i = l_i * alpha + rs;
    m_i = m_new;
#pragma unroll
    for (int n = 0; n < 4; n++)
#pragma unroll
      for (int r = 0; r < 4; r++) acc[n][r] *= alpha;

    U4 P0, P1;  // in-lane fragment assembly (key permutation makes this legal)
    P0.u[0] = pk2(p[0][0], p[0][1]); P0.u[1] = pk2(p[0][2], p[0][3]);
    P0.u[2] = pk2(p[2][0], p[2][1]); P0.u[3] = pk2(p[2][2], p[2][3]);
    P1.u[0] = pk2(p[1][0], p[1][1]); P1.u[1] = pk2(p[1][2], p[1][3]);
    P1.u[2] = pk2(p[3][0], p[3][1]); P1.u[3] = pk2(p[3][2], p[3][3]);

#pragma unroll
    for (int n = 0; n < 4; n++) {
      bf16x8 v0 = *(const bf16x8*)&Vs[(n * 16 + ml) * 64 + ((quad ^ cx) * 8)];
      bf16x8 v1 = *(const bf16x8*)&Vs[(n * 16 + ml) * 64 + (((quad + 4) ^ cx) * 8)];
      acc[n] = __builtin_amdgcn_mfma_f32_16x16x32_bf16(v0, P0.v, acc[n], 0, 0, 0);
      acc[n] = __builtin_amdgcn_mfma_f32_16x16x32_bf16(v1, P1.v, acc[n], 0, 0, 0);
    }
  }

  // epilogue: O^T (per-lane q=ml) -> LDS [q][d] stride 72 -> coalesced stores
  const float inv = 1.0f / l_i;
#pragma unroll
  for (int n = 0; n < 4; n++)
#pragma unroll
    for (int rp = 0; rp < 2; rp++) {
      unsigned int u = pk2(acc[n][2 * rp] * inv, acc[n][2 * rp + 1] * inv);
      *(unsigned int*)&Qs[(wave * 16 + ml) * 72 + n * 16 + quad * 4 + 2 * rp] = u;
    }
  __syncthreads();
  {
    const int q = t >> 2, d0 = (t & 3) * 16;
    unsigned short* og = O + ((size_t)(b * T_SEQ + q0 + q)) * 1024 + h * 64 + d0;
    *(int4*)og = *(const int4*)&Qs[q * 72 + d0];
    *(int4*)(og + 8) = *(const int4*)&Qs[q * 72 + d0 + 8];
  }
}

// ---------------------------------------------------------------------------
extern "C" void kernel_launch(void* const* d_in, const int* in_sizes, int n_in,
                              void* d_out, int out_size, void* d_ws,
                              size_t ws_size, hipStream_t stream) {
  (void)in_sizes; (void)n_in; (void)out_size; (void)ws_size;
  const size_t MEG = 1048576;
  unsigned short* ws16 = (unsigned short*)d_ws;
  char* wsb = (char*)d_ws;

  unsigned short* wt[10];
  for (int i = 0; i < 8; i++) wt[i] = ws16 + (size_t)i * MEG;
  wt[8] = ws16 + 8 * MEG;
  wt[9] = ws16 + 12 * MEG;
  unsigned short* encB  = ws16 + 16 * MEG;  // 4M
  unsigned short* hbuf  = ws16 + 20 * MEG;  // 4M
  unsigned short* QKb   = ws16 + 24 * MEG;  // 8M  [4096][2048]
  unsigned short* Qb    = ws16 + 32 * MEG;  // 4M
  unsigned short* Kb    = ws16 + 36 * MEG;  // 4M
  unsigned short* Vb    = ws16 + 40 * MEG;  // 4M  V^T [1024][4096]
  unsigned short* attnb = ws16 + 44 * MEG;  // 4M
  unsigned short* ffh   = ws16 + 24 * MEG;  // 16M, reuses QKb/Qb/Kb (dead)
  float* xf32 = (float*)(wsb + 96 * MEG);   // fp32 residual stream, 16 MB
  float* pbuf = (float*)(wsb + 112 * MEG);  // 19456 floats
  int* flag   = (int*)(wsb + 113 * MEG);

  probe_dtype_kernel<<<1, 256, 0, stream>>>((const unsigned short*)d_in[0], flag);

  {
    WTbl tb;
    const int widx[10] = {3, 5, 7, 9, 11, 13, 15, 17, 19, 21};
    int st = 0;
    for (int i = 0; i < 10; i++) {
      tb.src[i] = d_in[widx[i]];
      tb.K[i] = (i == 9) ? 4096 : 1024;
      tb.N[i] = (i == 8) ? 4096 : 1024;
      tb.start[i] = st;
      st += (tb.K[i] / 32) * (tb.N[i] / 32);
      tb.dstoff[i] = (unsigned int)((i < 8) ? i * MEG : (i == 8 ? 8 * MEG : 12 * MEG));
    }
    wtrans_fused_kernel<<<16384, 256, 0, stream>>>(tb, ws16, flag);
  }

  cvt_to_f32_kernel<<<4096, 256, 0, stream>>>(d_in[0], xf32, 4194304, flag);
  cvt_to_bf16_kernel<<<2048, 256, 0, stream>>>(d_in[1], encB, 4194304, flag);

  {
    PTbl pt;
    const int pidx[19] = {4, 6, 8, 10, 12, 14, 16, 18,
                          20, 20, 20, 20, 22, 23, 24, 25, 26, 27, 28};
    for (int i = 0; i < 19; i++) pt.p[i] = d_in[pidx[i]];
    param_cvt_kernel<<<19, 256, 0, stream>>>(pt, pbuf, flag);
  }
  float* bqk_sa = pbuf;            // sa_bq ++ sa_bk (contiguous 2048)
  float* bv_sa  = pbuf + 2048;
  float* bo_sa  = pbuf + 3072;
  float* bq_ca  = pbuf + 4096;
  float* bk_ca  = pbuf + 5120;
  float* bv_ca  = pbuf + 6144;
  float* bo_ca  = pbuf + 7168;
  float* ff_b1p = pbuf + 8192;
  float* ff_b2p = pbuf + 12288;
  float* ln1g = pbuf + 13312; float* ln1b = pbuf + 14336;
  float* ln2g = pbuf + 15360; float* ln2b = pbuf + 16384;
  float* ln3g = pbuf + 17408; float* ln3b = pbuf + 18432;

  dim3 gQK(16, 32);   // N=2048, BM=128/BN=128 -> 512 blocks
  dim3 gP(16, 32);    // N=1024, BM=128/BN=64  -> 512 blocks
  dim3 gVT(64, 8);    // M=1024/N=4096, BM=128/BN=64 -> 512 blocks
  dim3 gFF1(32, 32);  // N=4096, BM=128/BN=128 -> 1024 blocks
  dim3 gFF2(8, 64);   // N=1024, BM=64/BN=128  -> 512 blocks
  dim3 gAttn(32, 32);

  // ---- self attention ----
  ln_kernel<<<4096, 256, 0, stream>>>(xf32, ln1g, ln1b, hbuf);
  gemm_kernel<128, 128, 64, 0, 0, 1, 0, 2><<<gQK, 256, 0, stream>>>(
      hbuf, wt[0], bqk_sa, nullptr, QKb, NROWS, 2048, 1024, nullptr);
  gemm_kernel<128, 64, 64, 0, 0, 1, 1, 0><<<gVT, 256, 0, stream>>>(
      wt[2], hbuf, bv_sa, nullptr, Vb, 1024, 4096, 1024, nullptr);
  attn_kernel<1><<<gAttn, 256, 0, stream>>>(QKb, QKb + 1024, Vb, attnb, 2048, 2048);
  gemm_kernel<128, 64, 64, 0, 1, 0, 0, 0><<<gP, 256, 0, stream>>>(
      attnb, wt[3], bo_sa, xf32, xf32, NROWS, 1024, 1024, nullptr);

  // ---- cross attention ----
  ln_kernel<<<4096, 256, 0, stream>>>(xf32, ln2g, ln2b, hbuf);
  gemm_kernel<128, 64, 64, 0, 0, 1, 0, 1><<<gP, 256, 0, stream>>>(
      hbuf, wt[4], bq_ca, nullptr, Qb, NROWS, 1024, 1024, nullptr);
  gemm_kernel<128, 64, 64, 0, 0, 1, 0, 0><<<gP, 256, 0, stream>>>(
      encB, wt[5], bk_ca, nullptr, Kb, NROWS, 1024, 1024, nullptr);
  gemm_kernel<128, 64, 64, 0, 0, 1, 1, 0><<<gVT, 256, 0, stream>>>(
      wt[6], encB, bv_ca, nullptr, Vb, 1024, 4096, 1024, nullptr);
  attn_kernel<0><<<gAttn, 256, 0, stream>>>(Qb, Kb, Vb, attnb, 1024, 1024);
  gemm_kernel<128, 64, 64, 0, 1, 0, 0, 0><<<gP, 256, 0, stream>>>(
      attnb, wt[7], bo_ca, xf32, xf32, NROWS, 1024, 1024, nullptr);

  // ---- feed forward ----
  ln_kernel<<<4096, 256, 0, stream>>>(xf32, ln3g, ln3b, hbuf);
  gemm_kernel<128, 128, 64, 1, 0, 1, 0, 0><<<gFF1, 256, 0, stream>>>(
      hbuf, wt[8], ff_b1p, nullptr, ffh, NROWS, 4096, 1024, nullptr);
  gemm_kernel<64, 128, 64, 0, 1, 2, 0, 0><<<gFF2, 256, 0, stream>>>(
      ffh, wt[9], ff_b2p, xf32, d_out, NROWS, 1024, 4096, flag);
}

// Round 5
// 610.923 us; speedup vs baseline: 1.8214x; 1.0368x over previous
//
#include <hip/hip_runtime.h>
#include <stdint.h>

// ---------------------------------------------------------------------------
// TransformerDecoderLayer on gfx950: bf16 MFMA GEMMs + flash attention.
// B=2, T=S=2048, C=1024, H=16, D=64, FF=4096. 4096 token rows.
// R5: (a) attn softmax VALU diet — P fragments packed with v_perm_b32
// truncating fp32->bf16 (1 inst per pair vs ~12 for RNE); (b) GEMM group-8
// block swizzle so A-tile sharers hit the same XCD L2.
// ---------------------------------------------------------------------------

typedef __bf16 bf16x8 __attribute__((ext_vector_type(8)));
typedef float  f32x4  __attribute__((ext_vector_type(4)));

#define T_SEQ 2048
#define NROWS 4096   // B*T
#define QSCALE 0.18033688011112042f   // 0.125 * log2(e)

__device__ __forceinline__ unsigned short f2bf(float f) {
  union { float f; unsigned int u; } v; v.f = f;
  unsigned int u = v.u;
  return (unsigned short)((u + 0x7FFFu + ((u >> 16) & 1u)) >> 16);  // RNE
}
__device__ __forceinline__ float bf2f(unsigned short h) {
  union { unsigned int u; float f; } v; v.u = ((unsigned int)h) << 16;
  return v.f;
}
__device__ __forceinline__ unsigned int pk2(float a, float b) {
  return (unsigned int)f2bf(a) | ((unsigned int)f2bf(b) << 16);
}
// truncating pack: low16 = hi-half(a), high16 = hi-half(b) — one v_perm_b32
__device__ __forceinline__ unsigned int pk2t(float a, float b) {
  union { float f; unsigned int u; } ua, ub;
  ua.f = a; ub.f = b;
  return __builtin_amdgcn_perm(ub.u, ua.u, 0x07060302u);
}
union U4 { unsigned int u[4]; bf16x8 v; };

// ---------------------------------------------------------------------------
// dtype probe: bf16 (flag=1) vs fp32 (flag=0) input tensors.
// ---------------------------------------------------------------------------
__global__ void probe_dtype_kernel(const unsigned short* __restrict__ p,
                                   int* __restrict__ flag) {
  __shared__ int cnt;
  if (threadIdx.x == 0) cnt = 0;
  __syncthreads();
  int bad = 0;
  for (int i = threadIdx.x; i < 4096; i += 256) {
    unsigned short u = p[i];
    int e = (u >> 7) & 0xFF;
    if (u != 0 && (e < 100 || e > 140)) bad++;
  }
  atomicAdd(&cnt, bad);
  __syncthreads();
  if (threadIdx.x == 0) *flag = (cnt < 512) ? 1 : 0;
}

// ---------------------------------------------------------------------------
// Fused weight transpose+cast: all 10 weights in one dispatch (16384 blocks).
// ---------------------------------------------------------------------------
struct WTbl {
  const void* src[10];
  int K[10], N[10], start[10];
  unsigned int dstoff[10];  // in elements
};
__global__ void wtrans_fused_kernel(WTbl tbl, unsigned short* __restrict__ wsbase,
                                    const int* __restrict__ flag) {
  __shared__ unsigned short tile[32][33];
  const int lb = blockIdx.x;
  int wi = 0;
#pragma unroll
  for (int i = 1; i < 10; i++) wi = (lb >= tbl.start[i]) ? i : wi;
  const int local = lb - tbl.start[wi];
  const int Nw = tbl.N[wi], Kw = tbl.K[wi];
  const int bx = local & ((Nw >> 5) - 1);
  const int by = local / (Nw >> 5);
  const void* W = tbl.src[wi];
  unsigned short* Wt = wsbase + tbl.dstoff[wi];
  const int n0 = bx * 32, k0 = by * 32;
  const int c = threadIdx.x & 31, r0 = threadIdx.x >> 5;
  const bool isbf = (*flag != 0);
  for (int r = r0; r < 32; r += 8) {
    unsigned short v;
    if (isbf) v = ((const unsigned short*)W)[(size_t)(k0 + r) * Nw + n0 + c];
    else      v = f2bf(((const float*)W)[(size_t)(k0 + r) * Nw + n0 + c]);
    tile[r][c] = v;
  }
  __syncthreads();
  for (int r = r0; r < 32; r += 8)
    Wt[(size_t)(n0 + r) * Kw + k0 + c] = tile[c][r];
}

// ---------------------------------------------------------------------------
// Fused param convert: 19 x 1024 fp32 values into packed pbuf (one dispatch).
// ---------------------------------------------------------------------------
struct PTbl { const void* p[19]; };
__global__ void param_cvt_kernel(PTbl tbl, float* __restrict__ out,
                                 const int* __restrict__ flag) {
  const int blk = blockIdx.x;
  const int off = (blk >= 8 && blk < 12) ? (blk - 8) * 1024 : 0;
  const void* src = tbl.p[blk];
  const int i = threadIdx.x * 4;
  float4 o;
  if (*flag) {
    const unsigned short* u = (const unsigned short*)src + off;
    ushort4 q = *(const ushort4*)&u[i];
    o.x = bf2f(q.x); o.y = bf2f(q.y); o.z = bf2f(q.z); o.w = bf2f(q.w);
  } else {
    o = *(const float4*)&((const float*)src)[off + i];
  }
  *(float4*)&out[blk * 1024 + i] = o;
}

__global__ void cvt_to_bf16_kernel(const void* __restrict__ in,
                                   unsigned short* __restrict__ out,
                                   int n, const int* __restrict__ flag) {
  int i = (blockIdx.x * 256 + threadIdx.x) * 8;
  if (i >= n) return;
  if (*flag) {
    *(int4*)&out[i] = *(const int4*)&((const unsigned short*)in)[i];
  } else {
    const float* f = (const float*)in;
    float4 a = *(const float4*)&f[i];
    float4 c = *(const float4*)&f[i + 4];
    ushort4 o1, o2;
    o1.x = f2bf(a.x); o1.y = f2bf(a.y); o1.z = f2bf(a.z); o1.w = f2bf(a.w);
    o2.x = f2bf(c.x); o2.y = f2bf(c.y); o2.z = f2bf(c.z); o2.w = f2bf(c.w);
    *(ushort4*)&out[i] = o1;
    *(ushort4*)&out[i + 4] = o2;
  }
}

__global__ void cvt_to_f32_kernel(const void* __restrict__ in,
                                  float* __restrict__ out,
                                  int n, const int* __restrict__ flag) {
  int i = (blockIdx.x * 256 + threadIdx.x) * 4;
  if (i >= n) return;
  if (*flag) {
    const unsigned short* u = (const unsigned short*)in;
    ushort4 q = *(const ushort4*)&u[i];
    float4 o;
    o.x = bf2f(q.x); o.y = bf2f(q.y); o.z = bf2f(q.z); o.w = bf2f(q.w);
    *(float4*)&out[i] = o;
  } else {
    *(float4*)&out[i] = *(const float4*)&((const float*)in)[i];
  }
}

// LayerNorm over rows of 1024, fp32 in -> bf16 out
__global__ __launch_bounds__(256) void ln_kernel(
    const float* __restrict__ x, const float* __restrict__ g,
    const float* __restrict__ b, unsigned short* __restrict__ out) {
  const int row = blockIdx.x;
  const int t = threadIdx.x;
  const size_t base = (size_t)row * 1024;
  float4 v = *(const float4*)&x[base + t * 4];
  float s1 = v.x + v.y + v.z + v.w;
  float s2 = v.x * v.x + v.y * v.y + v.z * v.z + v.w * v.w;
#pragma unroll
  for (int d = 1; d < 64; d <<= 1) {
    s1 += __shfl_xor(s1, d, 64);
    s2 += __shfl_xor(s2, d, 64);
  }
  __shared__ float a1[4], a2[4];
  if ((t & 63) == 0) { a1[t >> 6] = s1; a2[t >> 6] = s2; }
  __syncthreads();
  s1 = a1[0] + a1[1] + a1[2] + a1[3];
  s2 = a2[0] + a2[1] + a2[2] + a2[3];
  const float mean = s1 * (1.0f / 1024.0f);
  const float var = s2 * (1.0f / 1024.0f) - mean * mean;
  const float rstd = rsqrtf(fmaxf(var, 0.0f) + 1e-5f);
  float4 gv = *(const float4*)&g[t * 4];
  float4 bv = *(const float4*)&b[t * 4];
  ushort4 o;
  o.x = f2bf((v.x - mean) * rstd * gv.x + bv.x);
  o.y = f2bf((v.y - mean) * rstd * gv.y + bv.y);
  o.z = f2bf((v.z - mean) * rstd * gv.z + bv.z);
  o.w = f2bf((v.w - mean) * rstd * gv.w + bv.w);
  *(ushort4*)&out[base + t * 4] = o;
}

// ---------------------------------------------------------------------------
// GEMM: C[M,N] = A[M,K](bf16) @ Bt[N,K](bf16)^T + bias (+relu) (+fp32 resid)
// BK=64, XOR-chunk-swizzled LDS. Group-8 block swizzle: blocks sharing an
// A-tile sit at lin===const (mod 8) -> same XCD -> A-tile pinned in one L2.
// OUTM: 0=f32 out, 1=bf16 out, 2=runtime flag (bf16 if *flag)
// BIASROW: bias indexed by row.  SCALEMODE: 0 none, 1 all *QSCALE,
// 2 cols<1024 *QSCALE (merged self-QK projection; K part unscaled).
// ---------------------------------------------------------------------------
template <int BM, int BN, int BK, int RELU, int RESID, int OUTM, int BIASROW,
          int SCALEMODE>
__global__ __launch_bounds__(256, 2) void gemm_kernel(
    const unsigned short* __restrict__ A, const unsigned short* __restrict__ Bt,
    const float* __restrict__ bias, const float* __restrict__ resid,
    void* __restrict__ outp, int M, int N, int K,
    const int* __restrict__ flag) {
  static_assert(BK == 64, "swizzle assumes 8 chunks/row");
  constexpr int WX = (BN == 64) ? 1 : 2;
  constexpr int WY = 4 / WX;
  constexpr int WM = BM / WY, WN = BN / WX;
  constexpr int MI = WM / 16, NJ = WN / 16;
  constexpr int ACALLS = BM * BK / 2048;
  constexpr int BCALLS = BN * BK / 2048;
  constexpr int RPC = 2048 / BK;  // rows staged per call (32)
  __shared__ unsigned short lsA[BM * BK];
  __shared__ unsigned short lsB[BN * BK];
  const int t = threadIdx.x;
  const int wave = t >> 6, lane = t & 63;
  const int ml = lane & 15, quad = lane >> 4;
  const int cx = ml & 7;          // read-side XOR key
  const int wm = (wave / WX) * WM, wn = (wave % WX) * WN;

  // group-8 L2-locality swizzle (bijective remap of block ids)
  const int nx = gridDim.x, ny = gridDim.y;
  const int lin = (int)blockIdx.y * nx + (int)blockIdx.x;
  const int per = 8 * nx;
  const int y0 = (lin / per) * 8;
  const int gsz = (ny - y0 < 8) ? (ny - y0) : 8;
  const int by = y0 + (lin % gsz);
  const int bx = (lin % per) / gsz;
  const size_t m0 = (size_t)by * BM;
  const size_t n0 = (size_t)bx * BN;

  f32x4 acc[MI][NJ];
  const f32x4 fz = {0.f, 0.f, 0.f, 0.f};
#pragma unroll
  for (int i = 0; i < MI; i++)
#pragma unroll
    for (int j = 0; j < NJ; j++) acc[i][j] = fz;

  const int rowL = t >> 3;                            // global row within tile
  const int colL = (((t & 7) ^ ((t >> 3) & 7)) * 8);  // swizzled source chunk
  const unsigned short* gA = A + (m0 + rowL) * (size_t)K + colL;
  const unsigned short* gB = Bt + (n0 + rowL) * (size_t)K + colL;

  for (int k0 = 0; k0 < K; k0 += BK) {
    __syncthreads();
#pragma unroll
    for (int c = 0; c < ACALLS; c++)
      __builtin_amdgcn_global_load_lds(
          (const __attribute__((address_space(1))) void*)(gA + (size_t)(c * RPC) * K + k0),
          (__attribute__((address_space(3))) void*)&lsA[c * 2048 + wave * 512], 16, 0, 0);
#pragma unroll
    for (int c = 0; c < BCALLS; c++)
      __builtin_amdgcn_global_load_lds(
          (const __attribute__((address_space(1))) void*)(gB + (size_t)(c * RPC) * K + k0),
          (__attribute__((address_space(3))) void*)&lsB[c * 2048 + wave * 512], 16, 0, 0);
    __syncthreads();
#pragma unroll
    for (int h = 0; h < BK / 32; h++) {
      bf16x8 af[MI], bfv[NJ];
#pragma unroll
      for (int i = 0; i < MI; i++)
        af[i] = *(const bf16x8*)
            &lsA[(wm + i * 16 + ml) * BK + (((h * 4 + quad) ^ cx) * 8)];
#pragma unroll
      for (int j = 0; j < NJ; j++)
        bfv[j] = *(const bf16x8*)
            &lsB[(wn + j * 16 + ml) * BK + (((h * 4 + quad) ^ cx) * 8)];
#pragma unroll
      for (int i = 0; i < MI; i++)
#pragma unroll
        for (int j = 0; j < NJ; j++)
          acc[i][j] = __builtin_amdgcn_mfma_f32_16x16x32_bf16(af[i], bfv[j],
                                                              acc[i][j], 0, 0, 0);
    }
  }

  const bool obf = (OUTM == 1) || (OUTM == 2 && *flag != 0);
#pragma unroll
  for (int j = 0; j < NJ; j++) {
    const size_t cg = n0 + wn + j * 16 + ml;
    const float bcol = BIASROW ? 0.0f : bias[cg];
    const float sc = (SCALEMODE == 0) ? 1.0f
                   : (SCALEMODE == 1) ? QSCALE
                                      : (cg < 1024 ? QSCALE : 1.0f);
#pragma unroll
    for (int i = 0; i < MI; i++) {
#pragma unroll
      for (int r = 0; r < 4; r++) {
        const size_t rg = m0 + wm + i * 16 + quad * 4 + r;
        const float bval = BIASROW ? bias[rg] : bcol;
        float v = (acc[i][j][r] + bval) * sc;
        if (RELU) v = fmaxf(v, 0.0f);
        if (RESID) v += resid[rg * N + cg];
        if (obf) ((unsigned short*)outp)[rg * N + cg] = f2bf(v);
        else     ((float*)outp)[rg * N + cg] = v;
      }
    }
  }
}

// ---------------------------------------------------------------------------
// Flash attention, S^T form, XOR-chunk-swizzled LDS, exp2 softmax.
// R5: P fragments assembled with truncating v_perm packs (pk2t).
// ---------------------------------------------------------------------------
template <int CAUSAL>
__global__ __launch_bounds__(256, 4) void attn_kernel(
    const unsigned short* __restrict__ Q, const unsigned short* __restrict__ K,
    const unsigned short* __restrict__ VT, unsigned short* __restrict__ O,
    int qstride, int kstride) {
  __shared__ unsigned short Ks[4096];   // [key_pos 64][d 64], rows permuted
  __shared__ unsigned short Vs[4096];   // [d 64][key 64]
  __shared__ unsigned short Qs[4608];   // [q 64][d 64]; epilogue [64][72]
  const int t = threadIdx.x;
  const int wave = t >> 6, lane = t & 63;
  const int ml = lane & 15, quad = lane >> 4;
  const int cx = ml & 7;  // read-side XOR key
  const int bh = blockIdx.y, b = bh >> 4, h = bh & 15;
  const int qb = CAUSAL ? ((int)gridDim.x - 1 - (int)blockIdx.x) : (int)blockIdx.x;
  const int q0 = qb * 64;
  const int lr = lane >> 3;
  const int scol = (((lane & 7) ^ lr) * 8);  // swizzled source chunk (stage)

  // stage Q [64][64] (once), swizzled
  {
    const unsigned short* g0 =
        Q + ((size_t)(b * T_SEQ + q0 + wave * 16 + lr)) * qstride + h * 64 + scol;
    __builtin_amdgcn_global_load_lds(
        (const __attribute__((address_space(1))) void*)g0,
        (__attribute__((address_space(3))) void*)&Qs[wave * 2 * 512], 16, 0, 0);
    const unsigned short* g1 = g0 + (size_t)8 * qstride;
    __builtin_amdgcn_global_load_lds(
        (const __attribute__((address_space(1))) void*)g1,
        (__attribute__((address_space(3))) void*)&Qs[(wave * 2 + 1) * 512], 16, 0, 0);
  }

  // per-lane permuted K source rows for this wave's 2 chunks
  int sp_[2];
#pragma unroll
  for (int i = 0; i < 2; i++) {
    int p = (wave * 2 + i) * 8 + lr;
    sp_[i] = ((p & 16) << 1) | ((p & 12) << 1) | ((p & 32) >> 3) | (p & 3);
  }
  const unsigned short* Kb_ = K + ((size_t)b * T_SEQ) * kstride + h * 64 + scol;
  const unsigned short* Vb_ = VT + ((size_t)h * 64) * 4096 + (size_t)b * T_SEQ + scol;

  __syncthreads();
  const bf16x8 aq0 = *(const bf16x8*)&Qs[(wave * 16 + ml) * 64 + ((quad ^ cx) * 8)];
  const bf16x8 aq1 = *(const bf16x8*)&Qs[(wave * 16 + ml) * 64 + (((quad + 4) ^ cx) * 8)];

  f32x4 acc[4];
  const f32x4 fz = {0.f, 0.f, 0.f, 0.f};
#pragma unroll
  for (int n = 0; n < 4; n++) acc[n] = fz;
  float m_i = -3.0e38f, l_i = 0.0f;
  const int q_glob = q0 + wave * 16 + ml;
  const int nkb = CAUSAL ? (qb + 1) : (T_SEQ / 64);

  for (int kb = 0; kb < nkb; kb++) {
    __syncthreads();
#pragma unroll
    for (int i = 0; i < 2; i++) {
      const int c = wave * 2 + i;
      const unsigned short* kg = Kb_ + ((size_t)(kb * 64 + sp_[i])) * kstride;
      __builtin_amdgcn_global_load_lds(
          (const __attribute__((address_space(1))) void*)kg,
          (__attribute__((address_space(3))) void*)&Ks[c * 512], 16, 0, 0);
      const unsigned short* vg = Vb_ + (size_t)(c * 8 + lr) * 4096 + kb * 64;
      __builtin_amdgcn_global_load_lds(
          (const __attribute__((address_space(1))) void*)vg,
          (__attribute__((address_space(3))) void*)&Vs[c * 512], 16, 0, 0);
    }
    __syncthreads();

    f32x4 s[4];
#pragma unroll
    for (int nt = 0; nt < 4; nt++) {
      bf16x8 k0 = *(const bf16x8*)&Ks[(nt * 16 + ml) * 64 + ((quad ^ cx) * 8)];
      bf16x8 k1 = *(const bf16x8*)&Ks[(nt * 16 + ml) * 64 + (((quad + 4) ^ cx) * 8)];
      f32x4 a = fz;
      a = __builtin_amdgcn_mfma_f32_16x16x32_bf16(k0, aq0, a, 0, 0, 0);
      a = __builtin_amdgcn_mfma_f32_16x16x32_bf16(k1, aq1, a, 0, 0, 0);
      s[nt] = a;
    }
    if (CAUSAL && kb == nkb - 1) {  // only the diagonal tile needs masking
#pragma unroll
      for (int nt = 0; nt < 4; nt++)
#pragma unroll
        for (int r = 0; r < 4; r++) {
          int key = kb * 64 + ((nt & 1) << 5) + (quad << 3) + ((nt >> 1) << 2) + r;
          if (key > q_glob) s[nt][r] = -3.0e38f;
        }
    }
    float tm = -3.0e38f;
#pragma unroll
    for (int nt = 0; nt < 4; nt++)
#pragma unroll
      for (int r = 0; r < 4; r++) tm = fmaxf(tm, s[nt][r]);
    tm = fmaxf(tm, __shfl_xor(tm, 16));
    tm = fmaxf(tm, __shfl_xor(tm, 32));
    const float m_new = fmaxf(m_i, tm);
    const float alpha = exp2f(m_i - m_new);
    float p[4][4];
    float rs = 0.f;
#pragma unroll
    for (int nt = 0; nt < 4; nt++)
#pragma unroll
      for (int r = 0; r < 4; r++) {
        p[nt][r] = exp2f(s[nt][r] - m_new);
        rs += p[nt][r];
      }
    rs += __shfl_xor(rs, 16);
    rs += __shfl_xor(rs, 32);
    l_i = l_i * alpha + rs;
    m_i = m_new;
#pragma unroll
    for (int n = 0; n < 4; n++)
#pragma unroll
      for (int r = 0; r < 4; r++) acc[n][r] *= alpha;

    U4 P0, P1;  // in-lane fragment assembly; truncating v_perm packs
    P0.u[0] = pk2t(p[0][0], p[0][1]); P0.u[1] = pk2t(p[0][2], p[0][3]);
    P0.u[2] = pk2t(p[2][0], p[2][1]); P0.u[3] = pk2t(p[2][2], p[2][3]);
    P1.u[0] = pk2t(p[1][0], p[1][1]); P1.u[1] = pk2t(p[1][2], p[1][3]);
    P1.u[2] = pk2t(p[3][0], p[3][1]); P1.u[3] = pk2t(p[3][2], p[3][3]);

#pragma unroll
    for (int n = 0; n < 4; n++) {
      bf16x8 v0 = *(const bf16x8*)&Vs[(n * 16 + ml) * 64 + ((quad ^ cx) * 8)];
      bf16x8 v1 = *(const bf16x8*)&Vs[(n * 16 + ml) * 64 + (((quad + 4) ^ cx) * 8)];
      acc[n] = __builtin_amdgcn_mfma_f32_16x16x32_bf16(v0, P0.v, acc[n], 0, 0, 0);
      acc[n] = __builtin_amdgcn_mfma_f32_16x16x32_bf16(v1, P1.v, acc[n], 0, 0, 0);
    }
  }

  // epilogue: O^T (per-lane q=ml) -> LDS [q][d] stride 72 -> coalesced stores
  const float inv = 1.0f / l_i;
#pragma unroll
  for (int n = 0; n < 4; n++)
#pragma unroll
    for (int rp = 0; rp < 2; rp++) {
      unsigned int u = pk2(acc[n][2 * rp] * inv, acc[n][2 * rp + 1] * inv);
      *(unsigned int*)&Qs[(wave * 16 + ml) * 72 + n * 16 + quad * 4 + 2 * rp] = u;
    }
  __syncthreads();
  {
    const int q = t >> 2, d0 = (t & 3) * 16;
    unsigned short* og = O + ((size_t)(b * T_SEQ + q0 + q)) * 1024 + h * 64 + d0;
    *(int4*)og = *(const int4*)&Qs[q * 72 + d0];
    *(int4*)(og + 8) = *(const int4*)&Qs[q * 72 + d0 + 8];
  }
}

// ---------------------------------------------------------------------------
extern "C" void kernel_launch(void* const* d_in, const int* in_sizes, int n_in,
                              void* d_out, int out_size, void* d_ws,
                              size_t ws_size, hipStream_t stream) {
  (void)in_sizes; (void)n_in; (void)out_size; (void)ws_size;
  const size_t MEG = 1048576;
  unsigned short* ws16 = (unsigned short*)d_ws;
  char* wsb = (char*)d_ws;

  unsigned short* wt[10];
  for (int i = 0; i < 8; i++) wt[i] = ws16 + (size_t)i * MEG;
  wt[8] = ws16 + 8 * MEG;
  wt[9] = ws16 + 12 * MEG;
  unsigned short* encB  = ws16 + 16 * MEG;  // 4M
  unsigned short* hbuf  = ws16 + 20 * MEG;  // 4M
  unsigned short* QKb   = ws16 + 24 * MEG;  // 8M  [4096][2048]
  unsigned short* Qb    = ws16 + 32 * MEG;  // 4M
  unsigned short* Kb    = ws16 + 36 * MEG;  // 4M
  unsigned short* Vb    = ws16 + 40 * MEG;  // 4M  V^T [1024][4096]
  unsigned short* attnb = ws16 + 44 * MEG;  // 4M
  unsigned short* ffh   = ws16 + 24 * MEG;  // 16M, reuses QKb/Qb/Kb (dead)
  float* xf32 = (float*)(wsb + 96 * MEG);   // fp32 residual stream, 16 MB
  float* pbuf = (float*)(wsb + 112 * MEG);  // 19456 floats
  int* flag   = (int*)(wsb + 113 * MEG);

  probe_dtype_kernel<<<1, 256, 0, stream>>>((const unsigned short*)d_in[0], flag);

  {
    WTbl tb;
    const int widx[10] = {3, 5, 7, 9, 11, 13, 15, 17, 19, 21};
    int st = 0;
    for (int i = 0; i < 10; i++) {
      tb.src[i] = d_in[widx[i]];
      tb.K[i] = (i == 9) ? 4096 : 1024;
      tb.N[i] = (i == 8) ? 4096 : 1024;
      tb.start[i] = st;
      st += (tb.K[i] / 32) * (tb.N[i] / 32);
      tb.dstoff[i] = (unsigned int)((i < 8) ? i * MEG : (i == 8 ? 8 * MEG : 12 * MEG));
    }
    wtrans_fused_kernel<<<16384, 256, 0, stream>>>(tb, ws16, flag);
  }

  cvt_to_f32_kernel<<<4096, 256, 0, stream>>>(d_in[0], xf32, 4194304, flag);
  cvt_to_bf16_kernel<<<2048, 256, 0, stream>>>(d_in[1], encB, 4194304, flag);

  {
    PTbl pt;
    const int pidx[19] = {4, 6, 8, 10, 12, 14, 16, 18,
                          20, 20, 20, 20, 22, 23, 24, 25, 26, 27, 28};
    for (int i = 0; i < 19; i++) pt.p[i] = d_in[pidx[i]];
    param_cvt_kernel<<<19, 256, 0, stream>>>(pt, pbuf, flag);
  }
  float* bqk_sa = pbuf;            // sa_bq ++ sa_bk (contiguous 2048)
  float* bv_sa  = pbuf + 2048;
  float* bo_sa  = pbuf + 3072;
  float* bq_ca  = pbuf + 4096;
  float* bk_ca  = pbuf + 5120;
  float* bv_ca  = pbuf + 6144;
  float* bo_ca  = pbuf + 7168;
  float* ff_b1p = pbuf + 8192;
  float* ff_b2p = pbuf + 12288;
  float* ln1g = pbuf + 13312; float* ln1b = pbuf + 14336;
  float* ln2g = pbuf + 15360; float* ln2b = pbuf + 16384;
  float* ln3g = pbuf + 17408; float* ln3b = pbuf + 18432;

  dim3 gQK(16, 32);   // N=2048, BM=128/BN=128 -> 512 blocks
  dim3 gP(16, 32);    // N=1024, BM=128/BN=64  -> 512 blocks
  dim3 gVT(64, 8);    // M=1024/N=4096, BM=128/BN=64 -> 512 blocks
  dim3 gFF1(32, 32);  // N=4096, BM=128/BN=128 -> 1024 blocks
  dim3 gFF2(8, 64);   // N=1024, BM=64/BN=128  -> 512 blocks
  dim3 gAttn(32, 32);

  // ---- self attention ----
  ln_kernel<<<4096, 256, 0, stream>>>(xf32, ln1g, ln1b, hbuf);
  gemm_kernel<128, 128, 64, 0, 0, 1, 0, 2><<<gQK, 256, 0, stream>>>(
      hbuf, wt[0], bqk_sa, nullptr, QKb, NROWS, 2048, 1024, nullptr);
  gemm_kernel<128, 64, 64, 0, 0, 1, 1, 0><<<gVT, 256, 0, stream>>>(
      wt[2], hbuf, bv_sa, nullptr, Vb, 1024, 4096, 1024, nullptr);
  attn_kernel<1><<<gAttn, 256, 0, stream>>>(QKb, QKb + 1024, Vb, attnb, 2048, 2048);
  gemm_kernel<128, 64, 64, 0, 1, 0, 0, 0><<<gP, 256, 0, stream>>>(
      attnb, wt[3], bo_sa, xf32, xf32, NROWS, 1024, 1024, nullptr);

  // ---- cross attention ----
  ln_kernel<<<4096, 256, 0, stream>>>(xf32, ln2g, ln2b, hbuf);
  gemm_kernel<128, 64, 64, 0, 0, 1, 0, 1><<<gP, 256, 0, stream>>>(
      hbuf, wt[4], bq_ca, nullptr, Qb, NROWS, 1024, 1024, nullptr);
  gemm_kernel<128, 64, 64, 0, 0, 1, 0, 0><<<gP, 256, 0, stream>>>(
      encB, wt[5], bk_ca, nullptr, Kb, NROWS, 1024, 1024, nullptr);
  gemm_kernel<128, 64, 64, 0, 0, 1, 1, 0><<<gVT, 256, 0, stream>>>(
      wt[6], encB, bv_ca, nullptr, Vb, 1024, 4096, 1024, nullptr);
  attn_kernel<0><<<gAttn, 256, 0, stream>>>(Qb, Kb, Vb, attnb, 1024, 1024);
  gemm_kernel<128, 64, 64, 0, 1, 0, 0, 0><<<gP, 256, 0, stream>>>(
      attnb, wt[7], bo_ca, xf32, xf32, NROWS, 1024, 1024, nullptr);

  // ---- feed forward ----
  ln_kernel<<<4096, 256, 0, stream>>>(xf32, ln3g, ln3b, hbuf);
  gemm_kernel<128, 128, 64, 1, 0, 1, 0, 0><<<gFF1, 256, 0, stream>>>(
      hbuf, wt[8], ff_b1p, nullptr, ffh, NROWS, 4096, 1024, nullptr);
  gemm_kernel<64, 128, 64, 0, 1, 2, 0, 0><<<gFF2, 256, 0, stream>>>(
      ffh, wt[9], ff_b2p, xf32, d_out, NROWS, 1024, 4096, flag);
}

// Round 6
// 558.201 us; speedup vs baseline: 1.9934x; 1.0944x over previous
//
#include <hip/hip_runtime.h>
#include <stdint.h>

// ---------------------------------------------------------------------------
// TransformerDecoderLayer on gfx950: bf16 MFMA GEMMs + flash attention.
// B=2, T=S=2048, C=1024, H=16, D=64, FF=4096. 4096 token rows.
// R6: (a) attn: per-lane l accumulation (sum shuffles hoisted out of the
// K-loop), __any-guarded max-rescale skip, raw v_exp_f32, pointer
// strength-reduction; (b) independent projection GEMMs fused into
// multi-segment dispatches (1536 blocks = 6 blocks/CU co-residency).
// ---------------------------------------------------------------------------

typedef __bf16 bf16x8 __attribute__((ext_vector_type(8)));
typedef float  f32x4  __attribute__((ext_vector_type(4)));

#define T_SEQ 2048
#define NROWS 4096   // B*T
#define QSCALE 0.18033688011112042f   // 0.125 * log2(e)

__device__ __forceinline__ unsigned short f2bf(float f) {
  union { float f; unsigned int u; } v; v.f = f;
  unsigned int u = v.u;
  return (unsigned short)((u + 0x7FFFu + ((u >> 16) & 1u)) >> 16);  // RNE
}
__device__ __forceinline__ float bf2f(unsigned short h) {
  union { unsigned int u; float f; } v; v.u = ((unsigned int)h) << 16;
  return v.f;
}
__device__ __forceinline__ unsigned int pk2(float a, float b) {
  return (unsigned int)f2bf(a) | ((unsigned int)f2bf(b) << 16);
}
// truncating pack: low16 = hi-half(a), high16 = hi-half(b) — one v_perm_b32
__device__ __forceinline__ unsigned int pk2t(float a, float b) {
  union { float f; unsigned int u; } ua, ub;
  ua.f = a; ub.f = b;
  return __builtin_amdgcn_perm(ub.u, ua.u, 0x07060302u);
}
__device__ __forceinline__ float fexp2(float x) {
  return __builtin_amdgcn_exp2f(x);  // bare v_exp_f32
}
union U4 { unsigned int u[4]; bf16x8 v; };

// ---------------------------------------------------------------------------
// dtype probe: bf16 (flag=1) vs fp32 (flag=0) input tensors.
// ---------------------------------------------------------------------------
__global__ void probe_dtype_kernel(const unsigned short* __restrict__ p,
                                   int* __restrict__ flag) {
  __shared__ int cnt;
  if (threadIdx.x == 0) cnt = 0;
  __syncthreads();
  int bad = 0;
  for (int i = threadIdx.x; i < 4096; i += 256) {
    unsigned short u = p[i];
    int e = (u >> 7) & 0xFF;
    if (u != 0 && (e < 100 || e > 140)) bad++;
  }
  atomicAdd(&cnt, bad);
  __syncthreads();
  if (threadIdx.x == 0) *flag = (cnt < 512) ? 1 : 0;
}

// ---------------------------------------------------------------------------
// Fused weight transpose+cast: all 10 weights in one dispatch (16384 blocks).
// ---------------------------------------------------------------------------
struct WTbl {
  const void* src[10];
  int K[10], N[10], start[10];
  unsigned int dstoff[10];  // in elements
};
__global__ void wtrans_fused_kernel(WTbl tbl, unsigned short* __restrict__ wsbase,
                                    const int* __restrict__ flag) {
  __shared__ unsigned short tile[32][33];
  const int lb = blockIdx.x;
  int wi = 0;
#pragma unroll
  for (int i = 1; i < 10; i++) wi = (lb >= tbl.start[i]) ? i : wi;
  const int local = lb - tbl.start[wi];
  const int Nw = tbl.N[wi], Kw = tbl.K[wi];
  const int bx = local & ((Nw >> 5) - 1);
  const int by = local / (Nw >> 5);
  const void* W = tbl.src[wi];
  unsigned short* Wt = wsbase + tbl.dstoff[wi];
  const int n0 = bx * 32, k0 = by * 32;
  const int c = threadIdx.x & 31, r0 = threadIdx.x >> 5;
  const bool isbf = (*flag != 0);
  for (int r = r0; r < 32; r += 8) {
    unsigned short v;
    if (isbf) v = ((const unsigned short*)W)[(size_t)(k0 + r) * Nw + n0 + c];
    else      v = f2bf(((const float*)W)[(size_t)(k0 + r) * Nw + n0 + c]);
    tile[r][c] = v;
  }
  __syncthreads();
  for (int r = r0; r < 32; r += 8)
    Wt[(size_t)(n0 + r) * Kw + k0 + c] = tile[c][r];
}

// ---------------------------------------------------------------------------
// Fused param convert: 19 x 1024 fp32 values into packed pbuf (one dispatch).
// ---------------------------------------------------------------------------
struct PTbl { const void* p[19]; };
__global__ void param_cvt_kernel(PTbl tbl, float* __restrict__ out,
                                 const int* __restrict__ flag) {
  const int blk = blockIdx.x;
  const int off = (blk >= 8 && blk < 12) ? (blk - 8) * 1024 : 0;
  const void* src = tbl.p[blk];
  const int i = threadIdx.x * 4;
  float4 o;
  if (*flag) {
    const unsigned short* u = (const unsigned short*)src + off;
    ushort4 q = *(const ushort4*)&u[i];
    o.x = bf2f(q.x); o.y = bf2f(q.y); o.z = bf2f(q.z); o.w = bf2f(q.w);
  } else {
    o = *(const float4*)&((const float*)src)[off + i];
  }
  *(float4*)&out[blk * 1024 + i] = o;
}

__global__ void cvt_to_bf16_kernel(const void* __restrict__ in,
                                   unsigned short* __restrict__ out,
                                   int n, const int* __restrict__ flag) {
  int i = (blockIdx.x * 256 + threadIdx.x) * 8;
  if (i >= n) return;
  if (*flag) {
    *(int4*)&out[i] = *(const int4*)&((const unsigned short*)in)[i];
  } else {
    const float* f = (const float*)in;
    float4 a = *(const float4*)&f[i];
    float4 c = *(const float4*)&f[i + 4];
    ushort4 o1, o2;
    o1.x = f2bf(a.x); o1.y = f2bf(a.y); o1.z = f2bf(a.z); o1.w = f2bf(a.w);
    o2.x = f2bf(c.x); o2.y = f2bf(c.y); o2.z = f2bf(c.z); o2.w = f2bf(c.w);
    *(ushort4*)&out[i] = o1;
    *(ushort4*)&out[i + 4] = o2;
  }
}

__global__ void cvt_to_f32_kernel(const void* __restrict__ in,
                                  float* __restrict__ out,
                                  int n, const int* __restrict__ flag) {
  int i = (blockIdx.x * 256 + threadIdx.x) * 4;
  if (i >= n) return;
  if (*flag) {
    const unsigned short* u = (const unsigned short*)in;
    ushort4 q = *(const ushort4*)&u[i];
    float4 o;
    o.x = bf2f(q.x); o.y = bf2f(q.y); o.z = bf2f(q.z); o.w = bf2f(q.w);
    *(float4*)&out[i] = o;
  } else {
    *(float4*)&out[i] = *(const float4*)&((const float*)in)[i];
  }
}

// LayerNorm over rows of 1024, fp32 in -> bf16 out
__global__ __launch_bounds__(256) void ln_kernel(
    const float* __restrict__ x, const float* __restrict__ g,
    const float* __restrict__ b, unsigned short* __restrict__ out) {
  const int row = blockIdx.x;
  const int t = threadIdx.x;
  const size_t base = (size_t)row * 1024;
  float4 v = *(const float4*)&x[base + t * 4];
  float s1 = v.x + v.y + v.z + v.w;
  float s2 = v.x * v.x + v.y * v.y + v.z * v.z + v.w * v.w;
#pragma unroll
  for (int d = 1; d < 64; d <<= 1) {
    s1 += __shfl_xor(s1, d, 64);
    s2 += __shfl_xor(s2, d, 64);
  }
  __shared__ float a1[4], a2[4];
  if ((t & 63) == 0) { a1[t >> 6] = s1; a2[t >> 6] = s2; }
  __syncthreads();
  s1 = a1[0] + a1[1] + a1[2] + a1[3];
  s2 = a2[0] + a2[1] + a2[2] + a2[3];
  const float mean = s1 * (1.0f / 1024.0f);
  const float var = s2 * (1.0f / 1024.0f) - mean * mean;
  const float rstd = rsqrtf(fmaxf(var, 0.0f) + 1e-5f);
  float4 gv = *(const float4*)&g[t * 4];
  float4 bv = *(const float4*)&b[t * 4];
  ushort4 o;
  o.x = f2bf((v.x - mean) * rstd * gv.x + bv.x);
  o.y = f2bf((v.y - mean) * rstd * gv.y + bv.y);
  o.z = f2bf((v.z - mean) * rstd * gv.z + bv.z);
  o.w = f2bf((v.w - mean) * rstd * gv.w + bv.w);
  *(ushort4*)&out[base + t * 4] = o;
}

// ---------------------------------------------------------------------------
// Single-segment GEMM (O-proj, FF1, FF2): same K-loop as before.
// ---------------------------------------------------------------------------
template <int BM, int BN, int BK, int RELU, int RESID, int OUTM, int BIASROW,
          int SCALEMODE>
__global__ __launch_bounds__(256, 2) void gemm_kernel(
    const unsigned short* __restrict__ A, const unsigned short* __restrict__ Bt,
    const float* __restrict__ bias, const float* __restrict__ resid,
    void* __restrict__ outp, int M, int N, int K,
    const int* __restrict__ flag) {
  static_assert(BK == 64, "swizzle assumes 8 chunks/row");
  constexpr int WX = (BN == 64) ? 1 : 2;
  constexpr int WY = 4 / WX;
  constexpr int WM = BM / WY, WN = BN / WX;
  constexpr int MI = WM / 16, NJ = WN / 16;
  constexpr int ACALLS = BM * BK / 2048;
  constexpr int BCALLS = BN * BK / 2048;
  constexpr int RPC = 2048 / BK;
  __shared__ unsigned short lsA[BM * BK];
  __shared__ unsigned short lsB[BN * BK];
  const int t = threadIdx.x;
  const int wave = t >> 6, lane = t & 63;
  const int ml = lane & 15, quad = lane >> 4;
  const int cx = ml & 7;
  const int wm = (wave / WX) * WM, wn = (wave % WX) * WN;

  const int nx = gridDim.x, ny = gridDim.y;
  const int lin = (int)blockIdx.y * nx + (int)blockIdx.x;
  const int per = 8 * nx;
  const int y0 = (lin / per) * 8;
  const int gsz = (ny - y0 < 8) ? (ny - y0) : 8;
  const int by = y0 + (lin % gsz);
  const int bx = (lin % per) / gsz;
  const size_t m0 = (size_t)by * BM;
  const size_t n0 = (size_t)bx * BN;

  f32x4 acc[MI][NJ];
  const f32x4 fz = {0.f, 0.f, 0.f, 0.f};
#pragma unroll
  for (int i = 0; i < MI; i++)
#pragma unroll
    for (int j = 0; j < NJ; j++) acc[i][j] = fz;

  const int rowL = t >> 3;
  const int colL = (((t & 7) ^ ((t >> 3) & 7)) * 8);
  const unsigned short* gA = A + (m0 + rowL) * (size_t)K + colL;
  const unsigned short* gB = Bt + (n0 + rowL) * (size_t)K + colL;

  for (int k0 = 0; k0 < K; k0 += BK) {
    __syncthreads();
#pragma unroll
    for (int c = 0; c < ACALLS; c++)
      __builtin_amdgcn_global_load_lds(
          (const __attribute__((address_space(1))) void*)(gA + (size_t)(c * RPC) * K + k0),
          (__attribute__((address_space(3))) void*)&lsA[c * 2048 + wave * 512], 16, 0, 0);
#pragma unroll
    for (int c = 0; c < BCALLS; c++)
      __builtin_amdgcn_global_load_lds(
          (const __attribute__((address_space(1))) void*)(gB + (size_t)(c * RPC) * K + k0),
          (__attribute__((address_space(3))) void*)&lsB[c * 2048 + wave * 512], 16, 0, 0);
    __syncthreads();
#pragma unroll
    for (int h = 0; h < BK / 32; h++) {
      bf16x8 af[MI], bfv[NJ];
#pragma unroll
      for (int i = 0; i < MI; i++)
        af[i] = *(const bf16x8*)
            &lsA[(wm + i * 16 + ml) * BK + (((h * 4 + quad) ^ cx) * 8)];
#pragma unroll
      for (int j = 0; j < NJ; j++)
        bfv[j] = *(const bf16x8*)
            &lsB[(wn + j * 16 + ml) * BK + (((h * 4 + quad) ^ cx) * 8)];
#pragma unroll
      for (int i = 0; i < MI; i++)
#pragma unroll
        for (int j = 0; j < NJ; j++)
          acc[i][j] = __builtin_amdgcn_mfma_f32_16x16x32_bf16(af[i], bfv[j],
                                                              acc[i][j], 0, 0, 0);
    }
  }

  const bool obf = (OUTM == 1) || (OUTM == 2 && *flag != 0);
#pragma unroll
  for (int j = 0; j < NJ; j++) {
    const size_t cg = n0 + wn + j * 16 + ml;
    const float bcol = BIASROW ? 0.0f : bias[cg];
    const float sc = (SCALEMODE == 0) ? 1.0f
                   : (SCALEMODE == 1) ? QSCALE
                                      : (cg < 1024 ? QSCALE : 1.0f);
#pragma unroll
    for (int i = 0; i < MI; i++) {
#pragma unroll
      for (int r = 0; r < 4; r++) {
        const size_t rg = m0 + wm + i * 16 + quad * 4 + r;
        const float bval = BIASROW ? bias[rg] : bcol;
        float v = (acc[i][j][r] + bval) * sc;
        if (RELU) v = fmaxf(v, 0.0f);
        if (RESID) v += resid[rg * N + cg];
        if (obf) ((unsigned short*)outp)[rg * N + cg] = f2bf(v);
        else     ((float*)outp)[rg * N + cg] = v;
      }
    }
  }
}

// ---------------------------------------------------------------------------
// Multi-segment GEMM: several independent 128x64x64 GEMMs in one dispatch.
// mode bits: 1=bias-by-row, 2=scale-all(QSCALE), 4=scale cols<1024(QSCALE).
// Output always bf16. Group-8 swizzle within each segment.
// ---------------------------------------------------------------------------
struct GSeg {
  const unsigned short* A; const unsigned short* B;
  const float* bias; unsigned short* out;
  int N, K, start, gxlog2, mode;
};
template <int NSEG>
__global__ __launch_bounds__(256, 4) void gemm_multi_kernel(GSeg s0, GSeg s1,
                                                            GSeg s2) {
  constexpr int BM = 128, BN = 64, BK = 64;
  constexpr int WM = 32, WN = 64;  // WX=1, WY=4
  constexpr int MI = 2, NJ = 4;
  __shared__ unsigned short lsA[BM * BK];
  __shared__ unsigned short lsB[BN * BK];
  const int blk = (int)blockIdx.x;
  GSeg sg = s0;
  if (NSEG > 1 && blk >= s1.start) sg = s1;
  if (NSEG > 2 && blk >= s2.start) sg = s2;
  const int t = threadIdx.x;
  const int wave = t >> 6, lane = t & 63;
  const int ml = lane & 15, quad = lane >> 4;
  const int cx = ml & 7;
  const int wm = wave * WM, wn = 0;
  const int N = sg.N, K = sg.K;

  const int lin = blk - sg.start;
  const int per = 8 << sg.gxlog2;
  const int y0 = (lin / per) * 8;                 // ny is a multiple of 8 here
  const int by = y0 + (lin & 7);
  const int bx = (lin & (per - 1)) >> 3;
  const size_t m0 = (size_t)by * BM;
  const size_t n0 = (size_t)bx * BN;

  f32x4 acc[MI][NJ];
  const f32x4 fz = {0.f, 0.f, 0.f, 0.f};
#pragma unroll
  for (int i = 0; i < MI; i++)
#pragma unroll
    for (int j = 0; j < NJ; j++) acc[i][j] = fz;

  const int rowL = t >> 3;
  const int colL = (((t & 7) ^ ((t >> 3) & 7)) * 8);
  const unsigned short* gA = sg.A + (m0 + rowL) * (size_t)K + colL;
  const unsigned short* gB = sg.B + (n0 + rowL) * (size_t)K + colL;

  for (int k0 = 0; k0 < K; k0 += BK) {
    __syncthreads();
#pragma unroll
    for (int c = 0; c < 4; c++)
      __builtin_amdgcn_global_load_lds(
          (const __attribute__((address_space(1))) void*)(gA + (size_t)(c * 32) * K + k0),
          (__attribute__((address_space(3))) void*)&lsA[c * 2048 + wave * 512], 16, 0, 0);
#pragma unroll
    for (int c = 0; c < 2; c++)
      __builtin_amdgcn_global_load_lds(
          (const __attribute__((address_space(1))) void*)(gB + (size_t)(c * 32) * K + k0),
          (__attribute__((address_space(3))) void*)&lsB[c * 2048 + wave * 512], 16, 0, 0);
    __syncthreads();
#pragma unroll
    for (int h = 0; h < BK / 32; h++) {
      bf16x8 af[MI], bfv[NJ];
#pragma unroll
      for (int i = 0; i < MI; i++)
        af[i] = *(const bf16x8*)
            &lsA[(wm + i * 16 + ml) * BK + (((h * 4 + quad) ^ cx) * 8)];
#pragma unroll
      for (int j = 0; j < NJ; j++)
        bfv[j] = *(const bf16x8*)
            &lsB[(wn + j * 16 + ml) * BK + (((h * 4 + quad) ^ cx) * 8)];
#pragma unroll
      for (int i = 0; i < MI; i++)
#pragma unroll
        for (int j = 0; j < NJ; j++)
          acc[i][j] = __builtin_amdgcn_mfma_f32_16x16x32_bf16(af[i], bfv[j],
                                                              acc[i][j], 0, 0, 0);
    }
  }

  const int mode = sg.mode;
#pragma unroll
  for (int j = 0; j < NJ; j++) {
    const size_t cg = n0 + wn + j * 16 + ml;
    const float bcol = (mode & 1) ? 0.0f : sg.bias[cg];
    const float sc = (mode & 2) ? QSCALE
                   : ((mode & 4) && cg < 1024) ? QSCALE : 1.0f;
#pragma unroll
    for (int i = 0; i < MI; i++) {
#pragma unroll
      for (int r = 0; r < 4; r++) {
        const size_t rg = m0 + wm + i * 16 + quad * 4 + r;
        const float bval = (mode & 1) ? sg.bias[rg] : bcol;
        float v = (acc[i][j][r] + bval) * sc;
        sg.out[rg * N + cg] = f2bf(v);
      }
    }
  }
}

// ---------------------------------------------------------------------------
// Flash attention, S^T form, XOR-chunk-swizzled LDS, base-2 softmax.
// R6: per-lane l accumulation (no per-iter sum shuffles), __any-guarded
// rescale skip, bare v_exp_f32, pointer increments.
// ---------------------------------------------------------------------------
template <int CAUSAL>
__global__ __launch_bounds__(256, 4) void attn_kernel(
    const unsigned short* __restrict__ Q, const unsigned short* __restrict__ K,
    const unsigned short* __restrict__ VT, unsigned short* __restrict__ O,
    int qstride, int kstride) {
  __shared__ unsigned short Ks[4096];   // [key_pos 64][d 64], rows permuted
  __shared__ unsigned short Vs[4096];   // [d 64][key 64]
  __shared__ unsigned short Qs[4608];   // [q 64][d 64]; epilogue [64][72]
  const int t = threadIdx.x;
  const int wave = t >> 6, lane = t & 63;
  const int ml = lane & 15, quad = lane >> 4;
  const int cx = ml & 7;
  const int bh = blockIdx.y, b = bh >> 4, h = bh & 15;
  const int qb = CAUSAL ? ((int)gridDim.x - 1 - (int)blockIdx.x) : (int)blockIdx.x;
  const int q0 = qb * 64;
  const int lr = lane >> 3;
  const int scol = (((lane & 7) ^ lr) * 8);

  // stage Q [64][64] (once), swizzled
  {
    const unsigned short* g0 =
        Q + ((size_t)(b * T_SEQ + q0 + wave * 16 + lr)) * qstride + h * 64 + scol;
    __builtin_amdgcn_global_load_lds(
        (const __attribute__((address_space(1))) void*)g0,
        (__attribute__((address_space(3))) void*)&Qs[wave * 2 * 512], 16, 0, 0);
    const unsigned short* g1 = g0 + (size_t)8 * qstride;
    __builtin_amdgcn_global_load_lds(
        (const __attribute__((address_space(1))) void*)g1,
        (__attribute__((address_space(3))) void*)&Qs[(wave * 2 + 1) * 512], 16, 0, 0);
  }

  // per-lane permuted K source rows for this wave's 2 chunks
  int sp_[2];
#pragma unroll
  for (int i = 0; i < 2; i++) {
    int p = (wave * 2 + i) * 8 + lr;
    sp_[i] = ((p & 16) << 1) | ((p & 12) << 1) | ((p & 32) >> 3) | (p & 3);
  }
  const unsigned short* kg0 =
      K + ((size_t)b * T_SEQ + sp_[0]) * kstride + h * 64 + scol;
  const unsigned short* kg1 =
      K + ((size_t)b * T_SEQ + sp_[1]) * kstride + h * 64 + scol;
  const unsigned short* vg0 =
      VT + ((size_t)(h * 64 + wave * 16 + lr)) * 4096 + (size_t)b * T_SEQ + scol;
  const unsigned short* vg1 = vg0 + (size_t)8 * 4096;

  __syncthreads();
  const bf16x8 aq0 = *(const bf16x8*)&Qs[(wave * 16 + ml) * 64 + ((quad ^ cx) * 8)];
  const bf16x8 aq1 = *(const bf16x8*)&Qs[(wave * 16 + ml) * 64 + (((quad + 4) ^ cx) * 8)];

  f32x4 acc[4];
  const f32x4 fz = {0.f, 0.f, 0.f, 0.f};
#pragma unroll
  for (int n = 0; n < 4; n++) acc[n] = fz;
  float m_i = -3.0e38f, l_part = 0.0f;
  const int q_glob = q0 + wave * 16 + ml;
  const int nkb = CAUSAL ? (qb + 1) : (T_SEQ / 64);
  const size_t kinc = (size_t)64 * kstride;

  for (int kb = 0; kb < nkb; kb++) {
    __syncthreads();
    __builtin_amdgcn_global_load_lds(
        (const __attribute__((address_space(1))) void*)kg0,
        (__attribute__((address_space(3))) void*)&Ks[(wave * 2) * 512], 16, 0, 0);
    __builtin_amdgcn_global_load_lds(
        (const __attribute__((address_space(1))) void*)kg1,
        (__attribute__((address_space(3))) void*)&Ks[(wave * 2 + 1) * 512], 16, 0, 0);
    __builtin_amdgcn_global_load_lds(
        (const __attribute__((address_space(1))) void*)vg0,
        (__attribute__((address_space(3))) void*)&Vs[(wave * 2) * 512], 16, 0, 0);
    __builtin_amdgcn_global_load_lds(
        (const __attribute__((address_space(1))) void*)vg1,
        (__attribute__((address_space(3))) void*)&Vs[(wave * 2 + 1) * 512], 16, 0, 0);
    kg0 += kinc; kg1 += kinc; vg0 += 64; vg1 += 64;
    __syncthreads();

    f32x4 s[4];
#pragma unroll
    for (int nt = 0; nt < 4; nt++) {
      bf16x8 k0 = *(const bf16x8*)&Ks[(nt * 16 + ml) * 64 + ((quad ^ cx) * 8)];
      bf16x8 k1 = *(const bf16x8*)&Ks[(nt * 16 + ml) * 64 + (((quad + 4) ^ cx) * 8)];
      f32x4 a = fz;
      a = __builtin_amdgcn_mfma_f32_16x16x32_bf16(k0, aq0, a, 0, 0, 0);
      a = __builtin_amdgcn_mfma_f32_16x16x32_bf16(k1, aq1, a, 0, 0, 0);
      s[nt] = a;
    }
    if (CAUSAL && kb == nkb - 1) {  // only the diagonal tile needs masking
#pragma unroll
      for (int nt = 0; nt < 4; nt++)
#pragma unroll
        for (int r = 0; r < 4; r++) {
          int key = kb * 64 + ((nt & 1) << 5) + (quad << 3) + ((nt >> 1) << 2) + r;
          if (key > q_glob) s[nt][r] = -3.0e38f;
        }
    }
    float tm = -3.0e38f;
#pragma unroll
    for (int nt = 0; nt < 4; nt++)
#pragma unroll
      for (int r = 0; r < 4; r++) tm = fmaxf(tm, s[nt][r]);
    tm = fmaxf(tm, __shfl_xor(tm, 16));
    tm = fmaxf(tm, __shfl_xor(tm, 32));
    if (__any(tm > m_i)) {
      const float m_new = fmaxf(m_i, tm);
      const float alpha = fexp2(m_i - m_new);
      l_part *= alpha;
#pragma unroll
      for (int n = 0; n < 4; n++)
#pragma unroll
        for (int r = 0; r < 4; r++) acc[n][r] *= alpha;
      m_i = m_new;
    }
    float p[4][4];
    float rs = 0.f;
#pragma unroll
    for (int nt = 0; nt < 4; nt++)
#pragma unroll
      for (int r = 0; r < 4; r++) {
        p[nt][r] = fexp2(s[nt][r] - m_i);
        rs += p[nt][r];
      }
    l_part += rs;  // cross-quad reduction deferred to the epilogue

    U4 P0, P1;  // in-lane fragment assembly; truncating v_perm packs
    P0.u[0] = pk2t(p[0][0], p[0][1]); P0.u[1] = pk2t(p[0][2], p[0][3]);
    P0.u[2] = pk2t(p[2][0], p[2][1]); P0.u[3] = pk2t(p[2][2], p[2][3]);
    P1.u[0] = pk2t(p[1][0], p[1][1]); P1.u[1] = pk2t(p[1][2], p[1][3]);
    P1.u[2] = pk2t(p[3][0], p[3][1]); P1.u[3] = pk2t(p[3][2], p[3][3]);

#pragma unroll
    for (int n = 0; n < 4; n++) {
      bf16x8 v0 = *(const bf16x8*)&Vs[(n * 16 + ml) * 64 + ((quad ^ cx) * 8)];
      bf16x8 v1 = *(const bf16x8*)&Vs[(n * 16 + ml) * 64 + (((quad + 4) ^ cx) * 8)];
      acc[n] = __builtin_amdgcn_mfma_f32_16x16x32_bf16(v0, P0.v, acc[n], 0, 0, 0);
      acc[n] = __builtin_amdgcn_mfma_f32_16x16x32_bf16(v1, P1.v, acc[n], 0, 0, 0);
    }
  }

  // final cross-quad l reduction (moved out of the K-loop)
  float l_i = l_part;
  l_i += __shfl_xor(l_i, 16);
  l_i += __shfl_xor(l_i, 32);

  // epilogue: O^T (per-lane q=ml) -> LDS [q][d] stride 72 -> coalesced stores
  const float inv = 1.0f / l_i;
#pragma unroll
  for (int n = 0; n < 4; n++)
#pragma unroll
    for (int rp = 0; rp < 2; rp++) {
      unsigned int u = pk2(acc[n][2 * rp] * inv, acc[n][2 * rp + 1] * inv);
      *(unsigned int*)&Qs[(wave * 16 + ml) * 72 + n * 16 + quad * 4 + 2 * rp] = u;
    }
  __syncthreads();
  {
    const int q = t >> 2, d0 = (t & 3) * 16;
    unsigned short* og = O + ((size_t)(b * T_SEQ + q0 + q)) * 1024 + h * 64 + d0;
    *(int4*)og = *(const int4*)&Qs[q * 72 + d0];
    *(int4*)(og + 8) = *(const int4*)&Qs[q * 72 + d0 + 8];
  }
}

// ---------------------------------------------------------------------------
extern "C" void kernel_launch(void* const* d_in, const int* in_sizes, int n_in,
                              void* d_out, int out_size, void* d_ws,
                              size_t ws_size, hipStream_t stream) {
  (void)in_sizes; (void)n_in; (void)out_size; (void)ws_size;
  const size_t MEG = 1048576;
  unsigned short* ws16 = (unsigned short*)d_ws;
  char* wsb = (char*)d_ws;

  unsigned short* wt[10];
  for (int i = 0; i < 8; i++) wt[i] = ws16 + (size_t)i * MEG;
  wt[8] = ws16 + 8 * MEG;
  wt[9] = ws16 + 12 * MEG;
  unsigned short* encB  = ws16 + 16 * MEG;  // 4M
  unsigned short* hbuf  = ws16 + 20 * MEG;  // 4M
  unsigned short* QKb   = ws16 + 24 * MEG;  // 8M  [4096][2048]
  unsigned short* Qb    = ws16 + 32 * MEG;  // 4M
  unsigned short* Kb    = ws16 + 36 * MEG;  // 4M
  unsigned short* Vb    = ws16 + 40 * MEG;  // 4M  V^T [1024][4096]
  unsigned short* attnb = ws16 + 44 * MEG;  // 4M
  unsigned short* ffh   = ws16 + 24 * MEG;  // 16M, reuses QKb/Qb/Kb (dead)
  float* xf32 = (float*)(wsb + 96 * MEG);   // fp32 residual stream, 16 MB
  float* pbuf = (float*)(wsb + 112 * MEG);  // 19456 floats
  int* flag   = (int*)(wsb + 113 * MEG);

  probe_dtype_kernel<<<1, 256, 0, stream>>>((const unsigned short*)d_in[0], flag);

  {
    WTbl tb;
    const int widx[10] = {3, 5, 7, 9, 11, 13, 15, 17, 19, 21};
    int st = 0;
    for (int i = 0; i < 10; i++) {
      tb.src[i] = d_in[widx[i]];
      tb.K[i] = (i == 9) ? 4096 : 1024;
      tb.N[i] = (i == 8) ? 4096 : 1024;
      tb.start[i] = st;
      st += (tb.K[i] / 32) * (tb.N[i] / 32);
      tb.dstoff[i] = (unsigned int)((i < 8) ? i * MEG : (i == 8 ? 8 * MEG : 12 * MEG));
    }
    wtrans_fused_kernel<<<16384, 256, 0, stream>>>(tb, ws16, flag);
  }

  cvt_to_f32_kernel<<<4096, 256, 0, stream>>>(d_in[0], xf32, 4194304, flag);
  cvt_to_bf16_kernel<<<2048, 256, 0, stream>>>(d_in[1], encB, 4194304, flag);

  {
    PTbl pt;
    const int pidx[19] = {4, 6, 8, 10, 12, 14, 16, 18,
                          20, 20, 20, 20, 22, 23, 24, 25, 26, 27, 28};
    for (int i = 0; i < 19; i++) pt.p[i] = d_in[pidx[i]];
    param_cvt_kernel<<<19, 256, 0, stream>>>(pt, pbuf, flag);
  }
  float* bqk_sa = pbuf;            // sa_bq ++ sa_bk (contiguous 2048)
  float* bv_sa  = pbuf + 2048;
  float* bo_sa  = pbuf + 3072;
  float* bq_ca  = pbuf + 4096;
  float* bk_ca  = pbuf + 5120;
  float* bv_ca  = pbuf + 6144;
  float* bo_ca  = pbuf + 7168;
  float* ff_b1p = pbuf + 8192;
  float* ff_b2p = pbuf + 12288;
  float* ln1g = pbuf + 13312; float* ln1b = pbuf + 14336;
  float* ln2g = pbuf + 15360; float* ln2b = pbuf + 16384;
  float* ln3g = pbuf + 17408; float* ln3b = pbuf + 18432;

  dim3 gP(16, 32);    // N=1024, BM=128/BN=64  -> 512 blocks
  dim3 gFF1(32, 32);  // N=4096, BM=128/BN=128 -> 1024 blocks
  dim3 gFF2(8, 64);   // N=1024, BM=64/BN=128  -> 512 blocks
  dim3 gAttn(32, 32);

  // ---- self attention ----
  ln_kernel<<<4096, 256, 0, stream>>>(xf32, ln1g, ln1b, hbuf);
  {
    // fused: QK projection (1024 blocks) + V^T projection (512 blocks)
    GSeg sQK = {hbuf, wt[0], bqk_sa, QKb, 2048, 1024, 0, 5, 4};
    GSeg sVT = {wt[2], hbuf, bv_sa, Vb, 4096, 1024, 1024, 6, 1};
    gemm_multi_kernel<2><<<1536, 256, 0, stream>>>(sQK, sVT, sVT);
  }
  attn_kernel<1><<<gAttn, 256, 0, stream>>>(QKb, QKb + 1024, Vb, attnb, 2048, 2048);
  gemm_kernel<128, 64, 64, 0, 1, 0, 0, 0><<<gP, 256, 0, stream>>>(
      attnb, wt[3], bo_sa, xf32, xf32, NROWS, 1024, 1024, nullptr);

  // ---- cross attention ----
  ln_kernel<<<4096, 256, 0, stream>>>(xf32, ln2g, ln2b, hbuf);
  {
    // fused: Q (512) + K (512) + V^T (512) projections
    GSeg sQ = {hbuf, wt[4], bq_ca, Qb, 1024, 1024, 0, 4, 2};
    GSeg sK = {encB, wt[5], bk_ca, Kb, 1024, 1024, 512, 4, 0};
    GSeg sV = {wt[6], encB, bv_ca, Vb, 4096, 1024, 1024, 6, 1};
    gemm_multi_kernel<3><<<1536, 256, 0, stream>>>(sQ, sK, sV);
  }
  attn_kernel<0><<<gAttn, 256, 0, stream>>>(Qb, Kb, Vb, attnb, 1024, 1024);
  gemm_kernel<128, 64, 64, 0, 1, 0, 0, 0><<<gP, 256, 0, stream>>>(
      attnb, wt[7], bo_ca, xf32, xf32, NROWS, 1024, 1024, nullptr);

  // ---- feed forward ----
  ln_kernel<<<4096, 256, 0, stream>>>(xf32, ln3g, ln3b, hbuf);
  gemm_kernel<128, 128, 64, 1, 0, 1, 0, 0><<<gFF1, 256, 0, stream>>>(
      hbuf, wt[8], ff_b1p, nullptr, ffh, NROWS, 4096, 1024, nullptr);
  gemm_kernel<64, 128, 64, 0, 1, 2, 0, 0><<<gFF2, 256, 0, stream>>>(
      ffh, wt[9], ff_b2p, xf32, d_out, NROWS, 1024, 4096, flag);
}